// Round 3
// baseline (14167.731 us; speedup 1.0000x reference)
//
#include <hip/hip_runtime.h>
#include <hip/hip_bf16.h>

using bf16 = __hip_bfloat16;
using uint = unsigned int;

__device__ __forceinline__ float b2f(bf16 x){ return __bfloat162float(x); }
__device__ __forceinline__ bf16  f2b(float x){ return __float2bfloat16(x); }
// bf16 bits of float with RNE (finite inputs)
__device__ __forceinline__ uint f2bu(float x){
    uint u = __float_as_uint(x);
    return (u + 0x7fffu + ((u >> 16) & 1u)) >> 16;
}

// ---------------- problem constants (fixed by setup_inputs) ----------------
constexpr int Mmol = 512, Aat = 64;
constexpr int Nat  = Mmol * Aat;      // 32768 real atoms
constexpr int NP1  = Nat + 1;         // 32769 rows (padding row 0)
constexpr int Bnd  = Nat * 4;         // 131072 directed bonds
constexpr int BP1  = Bnd + 1;         // 131073 rows
constexpr int Hd   = 300;
constexpr int AF   = 133, BFd = 147;
constexpr int NB   = 6;

// =====================================================================
// Tiled f32 GEMM:  C[n,h] = act( Asrc[n,k] @ W[h,k]^T (+bias)(+res) )
// 8x8 micro-tile, k-major LDS A tile (vectorized ds_read_b128 on both operands).
// A-operand modes:
//   0 = bf16 A direct
//   1 = f32 A direct
//   2 = f32 A with relu-on-load
//   3 = gathered A(row,kk) = A2[g1[row]*300+kk] - bf16 GB[g2[row]*300+kk]  (k==300)
//   4 = concat3 f32: kk<300 -> A, kk<600 -> A2, else A3 (row-stride 300, k==900)
// =====================================================================
constexpr int BMr = 256, BNc = 64, BKk = 8;

template<int AMODE, bool RELU, bool BIAS, bool RES, bool OUTBF16>
__global__ __launch_bounds__(256) void gemm_k(
    const void* __restrict__ A, const float* __restrict__ A2, const float* __restrict__ A3,
    const bf16* __restrict__ GB, const int* __restrict__ g1, const int* __restrict__ g2,
    const float* __restrict__ W, const float* __restrict__ bias, const bf16* __restrict__ res,
    void* __restrict__ Cp, int n, int k, int h)
{
    __shared__ float As[BKk][BMr];   // k-major: compute reads are b128
    __shared__ float Ws[BKk][BNc];

    const int tid = threadIdx.x;
    const int tx = tid & 7;          // 8 col-groups of 8
    const int ty = tid >> 3;         // 32 row-groups of 8
    const long rowBase = (long)blockIdx.x * BMr;
    const long colBase = (long)blockIdx.y * BNc;

    const long grow = rowBase + tid;      // staging: this thread's A row
    const bool rv = grow < n;
    long ra = 0, rb = 0;
    if constexpr (AMODE == 3) {
        ra = rv ? (long)g1[grow] : 0;
        rb = rv ? (long)g2[grow] : 0;
    }

    const int wcol = tid & 63, kh = tid >> 6;   // W staging: 64 cols x (4 groups of 2 kk)
    const long gcol = colBase + wcol;
    const bool cvv = gcol < h;

    float acc[8][8] = {};

    for (int kb = 0; kb < k; kb += BKk) {
        __syncthreads();
        // ---- stage A tile: each thread stages one row x 8 kk (transposed write) ----
        float av[8];
        #pragma unroll
        for (int c = 0; c < 8; ++c) {
            const int kk = kb + c;
            float v = 0.f;
            if (rv && kk < k) {
                if constexpr (AMODE == 0) {
                    v = b2f(((const bf16*)A)[grow * (long)k + kk]);
                } else if constexpr (AMODE == 1) {
                    v = ((const float*)A)[grow * (long)k + kk];
                } else if constexpr (AMODE == 2) {
                    v = fmaxf(((const float*)A)[grow * (long)k + kk], 0.f);
                } else if constexpr (AMODE == 3) {
                    v = A2[ra * 300 + kk] - b2f(GB[rb * 300 + kk]);
                } else if constexpr (AMODE == 4) {
                    v = (kk < 300) ? ((const float*)A)[grow * 300 + kk]
                      : (kk < 600) ? A2[grow * 300 + (kk - 300)]
                                   : A3[grow * 300 + (kk - 600)];
                }
            }
            av[c] = v;
        }
        #pragma unroll
        for (int c = 0; c < 8; ++c) As[c][tid] = av[c];
        // ---- stage W tile (k-major) ----
        #pragma unroll
        for (int c = 0; c < 2; ++c) {
            const int kk = kb + kh * 2 + c;
            Ws[kh * 2 + c][wcol] = (cvv && kk < k) ? W[gcol * (long)k + kk] : 0.f;
        }
        __syncthreads();
        // ---- compute 8x8 micro-tile over 8 kk ----
        #pragma unroll
        for (int kk = 0; kk < BKk; ++kk) {
            const float4 a0 = *(const float4*)&As[kk][ty * 8];
            const float4 a1 = *(const float4*)&As[kk][ty * 8 + 4];
            const float4 b0 = *(const float4*)&Ws[kk][tx * 8];
            const float4 b1 = *(const float4*)&Ws[kk][tx * 8 + 4];
            const float aa[8] = {a0.x,a0.y,a0.z,a0.w,a1.x,a1.y,a1.z,a1.w};
            const float bb[8] = {b0.x,b0.y,b0.z,b0.w,b1.x,b1.y,b1.z,b1.w};
            #pragma unroll
            for (int i = 0; i < 8; ++i)
                #pragma unroll
                for (int j = 0; j < 8; ++j)
                    acc[i][j] = fmaf(aa[i], bb[j], acc[i][j]);
        }
    }
    // ---- epilogue ----
    #pragma unroll
    for (int i = 0; i < 8; ++i) {
        const long r = rowBase + ty * 8 + i;
        if (r < n) {
            #pragma unroll
            for (int j = 0; j < 8; ++j) {
                const long c = colBase + tx * 8 + j;
                if (c < h) {
                    float v = acc[i][j];
                    if constexpr (RES)  v += b2f(res[r * (long)h + c]);
                    if constexpr (BIAS) v += bias[c];
                    if constexpr (RELU) v = fmaxf(v, 0.f);
                    if constexpr (OUTBF16) ((bf16*)Cp)[r * (long)h + c] = f2b(v);
                    else                   ((float*)Cp)[r * (long)h + c] = v;
                }
            }
        }
    }
}

// =====================================================================
// agg: out[row] = (src[atom]?) + sum_j(MB[a2b[atom][j]]) * max_j(...)
// =====================================================================
template<bool ADD>
__global__ __launch_bounds__(320) void agg_kernel(
    const bf16* __restrict__ MB, const int* __restrict__ a2b,
    const float* __restrict__ src, float* __restrict__ out, int rowoff)
{
    const int hh = threadIdx.x;
    if (hh >= Hd) return;
    const long atom = (long)blockIdx.x + rowoff;
    const int* nb = a2b + atom * NB;
    float s = 0.f, mx = -1e30f;
    #pragma unroll
    for (int j = 0; j < NB; ++j) {
        const float v = b2f(MB[(long)nb[j] * Hd + hh]);
        s += v; mx = fmaxf(mx, v);
    }
    const float agg = s * mx;
    const long o = (long)blockIdx.x * Hd + hh;
    if constexpr (ADD) out[o] = src[atom * Hd + hh] + agg;
    else               out[o] = agg;
}

// h0[m][hh] = max_a node[m*64+a][hh]   (node is pre-relu)
__global__ __launch_bounds__(320) void h0_kernel(const float* __restrict__ node, float* __restrict__ h0)
{
    const int hh = threadIdx.x;
    if (hh >= Hd) return;
    const long m = blockIdx.x;
    float mx = -1e30f;
    for (int a = 0; a < Aat; ++a)
        mx = fmaxf(mx, node[(m * Aat + a) * (long)Hd + hh]);
    h0[m * Hd + hh] = mx;
}

// out[m][hh] = mean_a AH[m*64+a][hh]
__global__ __launch_bounds__(320) void mean_kernel(const float* __restrict__ AH, float* __restrict__ out)
{
    const int hh = threadIdx.x;
    if (hh >= Hd) return;
    const long m = blockIdx.x;
    float s = 0.f;
    for (int a = 0; a < Aat; ++a)
        s += AH[(m * Aat + a) * (long)Hd + hh];
    out[m * Hd + hh] = s * (1.f / 64.f);
}

// =====================================================================
// Whh pre-pack: W [900][300] f32 -> WP [75][900] uint2 (4 bf16 along k, k-major)
// =====================================================================
__global__ __launch_bounds__(256) void pack_whh(const float* __restrict__ W, uint2* __restrict__ WP)
{
    const int idx = blockIdx.x * 256 + threadIdx.x;
    if (idx >= 75 * 900) return;
    const int k4 = idx / 900, r = idx - k4 * 900;
    const float* p = W + (long)r * 300 + k4 * 4;
    uint2 o;
    o.x = f2bu(p[0]) | (f2bu(p[1]) << 16);
    o.y = f2bu(p[2]) | (f2bu(p[3]) << 16);
    WP[idx] = o;
}

// =====================================================================
// Bidirectional batched GRU v2: one block = 4 molecules x 1 direction,
// 960 threads (15 waves). Phase 1: thread j computes gh row j (900 rows)
// for 4 mols, reading k-major packed bf16 Whh (coalesced uint2). Phase 2:
// gates + state update. h kept in LDS.
// =====================================================================
constexpr int GRU_G = 4;
constexpr int GRU_T = 960;

__global__ __launch_bounds__(GRU_T) void gru2_kernel(
    const bf16* __restrict__ gi_f, const bf16* __restrict__ gi_b,
    const uint2* __restrict__ WPf, const uint2* __restrict__ WPb,
    const float* __restrict__ bhh_f, const float* __restrict__ bhh_b,
    const float* __restrict__ h0, bf16* __restrict__ out)
{
    const int dir = blockIdx.x & 1;
    const int m0  = (blockIdx.x >> 1) * GRU_G;
    const uint2* WP  = dir ? WPb : WPf;
    const float* bhh = dir ? bhh_b : bhh_f;
    const bf16*  gi  = dir ? gi_b  : gi_f;

    __shared__ float Hs[GRU_G][304];    // padded rows: float4-aligned
    __shared__ float GHs[GRU_G][904];
    const int tid = threadIdx.x;
    const bool rOK = tid < 900;
    const float bb = rOK ? bhh[tid] : 0.f;

    for (int idx = tid; idx < GRU_G * Hd; idx += GRU_T) {
        const int g = idx / Hd, hh = idx - g * Hd;
        Hs[g][hh] = h0[(long)(m0 + g) * Hd + hh];
    }
    __syncthreads();

    for (int t = 0; t < Aat; ++t) {
        // ---- phase 1: gh[j] = dot(Whh[j,:], h[g,:]) + bhh[j] ----
        if (rOK) {
            float acc[GRU_G] = {};
            const uint2* wp = WP + tid;
            #pragma unroll 2
            for (int k4 = 0; k4 < 75; ++k4) {
                const uint2 u = wp[k4 * 900];
                const float w0 = __uint_as_float(u.x << 16);
                const float w1 = __uint_as_float(u.x & 0xffff0000u);
                const float w2 = __uint_as_float(u.y << 16);
                const float w3 = __uint_as_float(u.y & 0xffff0000u);
                #pragma unroll
                for (int g = 0; g < GRU_G; ++g) {
                    const float4 hv = *(const float4*)&Hs[g][k4 * 4];
                    acc[g] = fmaf(w0, hv.x, acc[g]);
                    acc[g] = fmaf(w1, hv.y, acc[g]);
                    acc[g] = fmaf(w2, hv.z, acc[g]);
                    acc[g] = fmaf(w3, hv.w, acc[g]);
                }
            }
            #pragma unroll
            for (int g = 0; g < GRU_G; ++g) GHs[g][tid] = acc[g] + bb;
        }
        __syncthreads();
        // ---- phase 2: gates + state update + output ----
        const int a = dir ? (Aat - 1 - t) : t;
        for (int idx = tid; idx < GRU_G * Hd; idx += GRU_T) {
            const int g = idx / Hd, hh = idx - g * Hd;
            const long row = (long)(m0 + g) * Aat + a;
            const bf16* girow = gi + row * 900;
            const float ir  = b2f(girow[hh]);
            const float iz  = b2f(girow[300 + hh]);
            const float inn = b2f(girow[600 + hh]);
            const float hr = GHs[g][hh], hz = GHs[g][300 + hh], hn = GHs[g][600 + hh];
            const float rr = 1.f / (1.f + __expf(-(ir + hr)));
            const float zz = 1.f / (1.f + __expf(-(iz + hz)));
            float nin = inn + rr * hn;
            nin = fminf(fmaxf(nin, -15.f), 15.f);
            const float e2 = __expf(-2.f * nin);
            const float nn = (1.f - e2) / (1.f + e2);
            const float hnew = (1.f - zz) * nn + zz * Hs[g][hh];
            Hs[g][hh] = hnew;                      // own element only: safe
            out[row * 600 + (long)dir * 300 + hh] = f2b(hnew);
        }
        __syncthreads();
    }
}

// =====================================================================
extern "C" void kernel_launch(void* const* d_in, const int* in_sizes, int n_in,
                              void* d_out, int out_size, void* d_ws, size_t ws_size,
                              hipStream_t stream)
{
    (void)in_sizes; (void)n_in; (void)out_size; (void)ws_size;

    const float* f_atoms  = (const float*)d_in[0];
    const float* f_bonds  = (const float*)d_in[1];
    const int*   a2b      = (const int*)d_in[2];
    const int*   b2a      = (const int*)d_in[3];
    const int*   b2revb   = (const int*)d_in[4];
    const float* W_i_atom = (const float*)d_in[7];
    const float* W_i_bond = (const float*)d_in[8];
    const float* W_h      = (const float*)d_in[9];    // [2,300,300]
    const float* lr_W     = (const float*)d_in[10];   // [300,900]
    const float* W_o_W    = (const float*)d_in[11];   // [300,600]
    const float* W_o_b    = (const float*)d_in[12];
    const float* gWih_f   = (const float*)d_in[13];
    const float* gWhh_f   = (const float*)d_in[14];
    const float* gbih_f   = (const float*)d_in[15];
    const float* gbhh_f   = (const float*)d_in[16];
    const float* gWih_b   = (const float*)d_in[17];
    const float* gWhh_b   = (const float*)d_in[18];
    const float* gbih_b   = (const float*)d_in[19];
    const float* gbhh_b   = (const float*)d_in[20];

    // ---- workspace layout (bump + liveness overlap; peak ~237 MB) ----
    const size_t IA_B   = (size_t)NP1 * Hd * 4;     // f32 atom tensors
    const size_t IB_B   = (size_t)BP1 * Hd * 2;     // bf16 bond tensors
    const size_t NODE_B = (size_t)Nat * Hd * 4;     // f32
    const size_t H0_B   = (size_t)Mmol * Hd * 4;

    size_t off = 0;
    auto alloc = [&](size_t b) { size_t r = off; off += (b + 255) & ~(size_t)255; return r; };
    const size_t ia_o = alloc(IA_B);
    const size_t ma_o = alloc(IA_B);
    const size_t r2_o = alloc(IB_B);   // IB -> MB1(in-place) -> gi_f -> AH
    const size_t r3_o = alloc(IB_B);   // MB0 -> (AGG | NODE) -> (gru_out | WhhPack)
    const size_t h0_o = alloc(H0_B);

    char* ws = (char*)d_ws;
    float* IA   = (float*)(ws + ia_o);
    float* MAb  = (float*)(ws + ma_o);
    bf16*  IB   = (bf16*)(ws + r2_o);
    bf16*  MB0  = (bf16*)(ws + r3_o);
    bf16*  MB1  = IB;                          // d=1 writes in place over IB
    float* AGG  = (float*)(ws + r3_o);         // after MB0 dead
    float* NODE = (float*)(ws + r3_o + NODE_B);
    bf16*  GIF  = (bf16*)(ws + r2_o);          // after MB1 dead (last read step 7)
    bf16*  GIB  = (bf16*)(ws + ia_o);          // after IA/MA dead (last read step 8)
    bf16*  GRU  = (bf16*)(ws + r3_o);          // over dead AGG
    uint2* WPf  = (uint2*)(ws + r3_o + NODE_B);        // over dead NODE (after steps 10/11)
    uint2* WPb  = WPf + 75 * 900;
    float* H0p  = (float*)(ws + h0_o);
    float* AH   = (float*)(ws + r2_o);         // over gi_f after GRU consumed it
    float* OUT  = (float*)d_out;

    const dim3 blk(256);
    auto grd = [](int n, int h) { return dim3((n + BMr - 1) / BMr, (h + BNc - 1) / BNc); };

    // 1. input_atom = relu(f_atoms @ W_i_atom^T)  -> f32
    gemm_k<1, true, false, false, false><<<grd(NP1, Hd), blk, 0, stream>>>(
        f_atoms, nullptr, nullptr, nullptr, nullptr, nullptr, W_i_atom, nullptr, nullptr,
        IA, NP1, AF, Hd);
    // 2. input_bond = relu(f_bonds @ W_i_bond^T)  -> bf16
    gemm_k<1, true, false, false, true><<<grd(BP1, Hd), blk, 0, stream>>>(
        f_bonds, nullptr, nullptr, nullptr, nullptr, nullptr, W_i_bond, nullptr, nullptr,
        IB, BP1, BFd, Hd);
    // 3. d=0 atom agg: MA = IA + sum*max(IB gathered)
    agg_kernel<true><<<NP1, 320, 0, stream>>>(IB, a2b, IA, MAb, 0);
    // 4. d=0 bond update: MB0 = relu(IB + (MA[b2a]-IB[b2revb]) @ Wh0^T)
    gemm_k<3, true, false, true, true><<<grd(BP1, Hd), blk, 0, stream>>>(
        nullptr, MAb, nullptr, IB, b2a, b2revb, W_h, nullptr, IB,
        MB0, BP1, Hd, Hd);
    // 5. d=1 atom agg: MA += sum*max(MB0 gathered)
    agg_kernel<true><<<NP1, 320, 0, stream>>>(MB0, a2b, MAb, MAb, 0);
    // 6. d=1 bond update: MB1(=IB region) = relu(IB + (MA[b2a]-MB0[b2revb]) @ Wh1^T)
    gemm_k<3, true, false, true, true><<<grd(BP1, Hd), blk, 0, stream>>>(
        nullptr, MAb, nullptr, MB0, b2a, b2revb, W_h + 300 * 300, nullptr, IB,
        MB1, BP1, Hd, Hd);
    // 7. final agg for atoms 1..N -> AGG
    agg_kernel<false><<<Nat, 320, 0, stream>>>(MB1, a2b, nullptr, AGG, 1);
    // 8. node = concat(AGG, MA, IA) @ lr_W^T   (pre-relu, atoms 1..N)
    gemm_k<4, false, false, false, false><<<grd(Nat, Hd), blk, 0, stream>>>(
        AGG, MAb + Hd, IA + Hd, nullptr, nullptr, nullptr, lr_W, nullptr, nullptr,
        NODE, Nat, 900, Hd);
    // 9. h0 = per-mol max of pre-relu node
    h0_kernel<<<Mmol, 320, 0, stream>>>(NODE, H0p);
    // 10/11. gi = relu(node) @ gWih^T + gbih  -> bf16
    gemm_k<2, false, true, false, true><<<grd(Nat, 900), blk, 0, stream>>>(
        NODE, nullptr, nullptr, nullptr, nullptr, nullptr, gWih_f, gbih_f, nullptr,
        GIF, Nat, Hd, 900);
    gemm_k<2, false, true, false, true><<<grd(Nat, 900), blk, 0, stream>>>(
        NODE, nullptr, nullptr, nullptr, nullptr, nullptr, gWih_b, gbih_b, nullptr,
        GIB, Nat, Hd, 900);
    // 11b. pack Whh (NODE now dead; WP lives in its region)
    pack_whh<<<(75 * 900 + 255) / 256, 256, 0, stream>>>(gWhh_f, WPf);
    pack_whh<<<(75 * 900 + 255) / 256, 256, 0, stream>>>(gWhh_b, WPb);
    // 12. bidirectional GRU scan -> bf16 [Nat, 600]
    gru2_kernel<<<(Mmol / GRU_G) * 2, GRU_T, 0, stream>>>(
        GIF, GIB, WPf, WPb, gbhh_f, gbhh_b, H0p, GRU);
    // 13. atom_hiddens = relu(gru_out @ W_o_W^T + W_o_b) -> f32 (atoms 1..N)
    gemm_k<0, true, true, false, false><<<grd(Nat, Hd), blk, 0, stream>>>(
        GRU, nullptr, nullptr, nullptr, nullptr, nullptr, W_o_W, W_o_b, nullptr,
        AH, Nat, 600, Hd);
    // 14. mol_vecs = mean over atoms -> f32 d_out
    mean_kernel<<<Mmol, 320, 0, stream>>>(AH, OUT);
}

// Round 5
// 4696.169 us; speedup vs baseline: 3.0169x; 3.0169x over previous
//
#include <hip/hip_runtime.h>
#include <hip/hip_bf16.h>

using bf16 = __hip_bfloat16;
using uint = unsigned int;

__device__ __forceinline__ float b2f(bf16 x){ return __bfloat162float(x); }
__device__ __forceinline__ bf16  f2b(float x){ return __float2bfloat16(x); }
// bf16 bits of float with RNE (finite inputs)
__device__ __forceinline__ uint f2bu(float x){
    uint u = __float_as_uint(x);
    return (u + 0x7fffu + ((u >> 16) & 1u)) >> 16;
}

// ---------------- problem constants (fixed by setup_inputs) ----------------
constexpr int Mmol = 512, Aat = 64;
constexpr int Nat  = Mmol * Aat;      // 32768 real atoms
constexpr int NP1  = Nat + 1;         // 32769 rows (padding row 0)
constexpr int Bnd  = Nat * 4;         // 131072 directed bonds
constexpr int BP1  = Bnd + 1;         // 131073 rows
constexpr int Hd   = 300;
constexpr int AF   = 133, BFd = 147;
constexpr int NB   = 6;

// =====================================================================
// Tiled f32 GEMM:  C[n,h] = act( Asrc[n,k] @ W[h,k]^T (+bias)(+res) )
// BK=16. A staging:
//   AMODE 0: bf16 A direct, thread-per-row (row k-slice = 32B contiguous)
//   AMODE 1: f32 A direct, thread-per-row scalar (odd k: 133/147)
//   AMODE 3: FUSED GATHER: A(row) = MA[g1[row]] - bf16 MB[g2[row]], k==300.
//            4 lanes per row: lane-quad q loads float4(MA)+uint2(MB) ->
//            every gathered row read as fully-used 64B segments (fixes the
//            R3 20x over-fetch WITHOUT materializing BA (R4 ws overflow)).
//   AMODE 4: concat3 f32 (AGG|MA|IA), row-stride 300, k==900
// DUAL: write Cp (f32, pre-relu) AND Cp2 (bf16, relu'd)
// =====================================================================
constexpr int BMr = 256, BNc = 64;
constexpr int ASTR = 260;   // As row stride: 16B-aligned rows, <=2-way LDS bank conflict

template<int AMODE, bool RELU, bool BIAS, bool RES, bool OUTBF16, bool DUAL>
__global__ __launch_bounds__(256) void gemm_k(
    const void* __restrict__ A, const float* __restrict__ A2, const float* __restrict__ A3,
    const int* __restrict__ g1, const int* __restrict__ g2,
    const float* __restrict__ W, const float* __restrict__ bias, const bf16* __restrict__ res,
    void* __restrict__ Cp, bf16* __restrict__ Cp2, int n, int k, int h)
{
    __shared__ float As[16][ASTR];
    __shared__ float Ws[16][BNc];
    __shared__ int   ras[BMr], rbs[BMr];

    const int tid = threadIdx.x;
    const int tx = tid & 7;          // 8 col-groups of 8
    const int ty = tid >> 3;         // 32 row-groups of 8
    const long rowBase = (long)blockIdx.x * BMr;
    const long colBase = (long)blockIdx.y * BNc;

    const long grow = rowBase + tid;      // staging: this thread's A row
    const bool rv = grow < n;

    if constexpr (AMODE == 3) {
        ras[tid] = rv ? g1[grow] : 0;
        rbs[tid] = rv ? g2[grow] : 0;
    }

    const int wcol = tid & 63, kq = tid >> 6;   // W staging: 64 cols x 4 k-quads
    const long gcol = colBase + wcol;
    const bool cvv = gcol < h;

    float acc[8][8] = {};

    const int ktiles = (k + 15) / 16;
    for (int kt = 0; kt < ktiles; ++kt) {
        const int kb = kt * 16;
        __syncthreads();            // also covers ras/rbs on first iteration
        // ---- stage A tile ----
        if constexpr (AMODE == 0) {
            const bf16* ap = (const bf16*)A + grow * (long)k + kb;
            if (rv && kb + 16 <= k) {
                #pragma unroll
                for (int c2 = 0; c2 < 4; ++c2) {            // 4 x uint2 (8B, aligned)
                    const uint2 u = *(const uint2*)(ap + c2 * 4);
                    As[c2*4+0][tid] = __uint_as_float(u.x << 16);
                    As[c2*4+1][tid] = __uint_as_float(u.x & 0xffff0000u);
                    As[c2*4+2][tid] = __uint_as_float(u.y << 16);
                    As[c2*4+3][tid] = __uint_as_float(u.y & 0xffff0000u);
                }
            } else {
                #pragma unroll
                for (int c = 0; c < 16; ++c)
                    As[c][tid] = (rv && kb + c < k) ? b2f(ap[c]) : 0.f;
            }
        } else if constexpr (AMODE == 1) {
            const float* ap = (const float*)A + grow * (long)k + kb;
            #pragma unroll
            for (int c = 0; c < 16; ++c)
                As[c][tid] = (rv && kb + c < k) ? ap[c] : 0.f;
        } else if constexpr (AMODE == 3) {
            // 4 lanes per row; rows indices from LDS (broadcast within quad)
            const int rl = tid >> 2, q = tid & 3;
            #pragma unroll
            for (int pass = 0; pass < 4; ++pass) {
                const int r = pass * 64 + rl;
                float v[4];
                if (rowBase + r < n) {
                    const long ra = ras[r], rb = rbs[r];
                    // vector loads; tail-tile OOB lanes masked below (reads
                    // stay inside d_ws: regions are contiguous + 256B pad)
                    const float4 ma = *(const float4*)(A2 + ra * 300 + kb + q * 4);
                    const uint2  mu = *(const uint2*)((const bf16*)A + rb * 300 + kb + q * 4);
                    v[0] = ma.x - __uint_as_float(mu.x << 16);
                    v[1] = ma.y - __uint_as_float(mu.x & 0xffff0000u);
                    v[2] = ma.z - __uint_as_float(mu.y << 16);
                    v[3] = ma.w - __uint_as_float(mu.y & 0xffff0000u);
                } else { v[0] = v[1] = v[2] = v[3] = 0.f; }
                #pragma unroll
                for (int j = 0; j < 4; ++j) {
                    const int kk = q * 4 + j;
                    As[kk][r] = (kb + kk < k) ? v[j] : 0.f;
                }
            }
        } else {  // AMODE 4: concat3
            #pragma unroll
            for (int c = 0; c < 16; ++c) {
                const int kk = kb + c;
                float v = 0.f;
                if (rv && kk < k) {
                    v = (kk < 300) ? ((const float*)A)[grow * 300 + kk]
                      : (kk < 600) ? A2[grow * 300 + (kk - 300)]
                                   : A3[grow * 300 + (kk - 600)];
                }
                As[c][tid] = v;
            }
        }
        // ---- stage W tile ----
        #pragma unroll
        for (int c = 0; c < 4; ++c) {
            const int kk = kb + kq * 4 + c;
            Ws[kq * 4 + c][wcol] = (cvv && kk < k) ? W[gcol * (long)k + kk] : 0.f;
        }
        __syncthreads();
        // ---- compute 8x8 micro-tile over 16 kk ----
        #pragma unroll
        for (int kk = 0; kk < 16; ++kk) {
            const float4 a0 = *(const float4*)&As[kk][ty * 8];
            const float4 a1 = *(const float4*)&As[kk][ty * 8 + 4];
            const float4 b0 = *(const float4*)&Ws[kk][tx * 8];
            const float4 b1 = *(const float4*)&Ws[kk][tx * 8 + 4];
            const float aa[8] = {a0.x,a0.y,a0.z,a0.w,a1.x,a1.y,a1.z,a1.w};
            const float bb[8] = {b0.x,b0.y,b0.z,b0.w,b1.x,b1.y,b1.z,b1.w};
            #pragma unroll
            for (int i = 0; i < 8; ++i)
                #pragma unroll
                for (int j = 0; j < 8; ++j)
                    acc[i][j] = fmaf(aa[i], bb[j], acc[i][j]);
        }
    }
    // ---- epilogue ----
    #pragma unroll
    for (int i = 0; i < 8; ++i) {
        const long r = rowBase + ty * 8 + i;
        if (r < n) {
            #pragma unroll
            for (int j = 0; j < 8; ++j) {
                const long c = colBase + tx * 8 + j;
                if (c < h) {
                    float v = acc[i][j];
                    if constexpr (RES)  v += b2f(res[r * (long)h + c]);
                    if constexpr (BIAS) v += bias[c];
                    if constexpr (RELU) v = fmaxf(v, 0.f);
                    if constexpr (DUAL) {
                        ((float*)Cp)[r * (long)h + c] = v;              // pre-relu f32
                        Cp2[r * (long)h + c] = f2b(fmaxf(v, 0.f));      // relu'd bf16
                    } else if constexpr (OUTBF16) {
                        ((bf16*)Cp)[r * (long)h + c] = f2b(v);
                    } else {
                        ((float*)Cp)[r * (long)h + c] = v;
                    }
                }
            }
        }
    }
}

// =====================================================================
// agg: out[row] = (src[atom]?) + sum_j(MB[a2b[atom][j]]) * max_j(...)
// =====================================================================
template<bool ADD>
__global__ __launch_bounds__(320) void agg_kernel(
    const bf16* __restrict__ MB, const int* __restrict__ a2b,
    const float* __restrict__ src, float* __restrict__ out, int rowoff)
{
    const int hh = threadIdx.x;
    if (hh >= Hd) return;
    const long atom = (long)blockIdx.x + rowoff;
    const int* nb = a2b + atom * NB;
    float s = 0.f, mx = -1e30f;
    #pragma unroll
    for (int j = 0; j < NB; ++j) {
        const float v = b2f(MB[(long)nb[j] * Hd + hh]);
        s += v; mx = fmaxf(mx, v);
    }
    const float agg = s * mx;
    const long o = (long)blockIdx.x * Hd + hh;
    if constexpr (ADD) out[o] = src[atom * Hd + hh] + agg;
    else               out[o] = agg;
}

// h0[m][hh] = max_a node[m*64+a][hh]   (node is pre-relu)
__global__ __launch_bounds__(320) void h0_kernel(const float* __restrict__ node, float* __restrict__ h0)
{
    const int hh = threadIdx.x;
    if (hh >= Hd) return;
    const long m = blockIdx.x;
    float mx = -1e30f;
    for (int a = 0; a < Aat; ++a)
        mx = fmaxf(mx, node[(m * Aat + a) * (long)Hd + hh]);
    h0[m * Hd + hh] = mx;
}

// out[m][hh] = mean_a AH[m*64+a][hh]
__global__ __launch_bounds__(320) void mean_kernel(const float* __restrict__ AH, float* __restrict__ out)
{
    const int hh = threadIdx.x;
    if (hh >= Hd) return;
    const long m = blockIdx.x;
    float s = 0.f;
    for (int a = 0; a < Aat; ++a)
        s += AH[(m * Aat + a) * (long)Hd + hh];
    out[m * Hd + hh] = s * (1.f / 64.f);
}

// =====================================================================
// Whh pre-pack: W [900][300] f32 -> WP [75][900] uint2 (4 bf16 along k, k-major)
// =====================================================================
__global__ __launch_bounds__(256) void pack_whh(const float* __restrict__ W, uint2* __restrict__ WP)
{
    const int idx = blockIdx.x * 256 + threadIdx.x;
    if (idx >= 75 * 900) return;
    const int k4 = idx / 900, r = idx - k4 * 900;
    const float* p = W + (long)r * 300 + k4 * 4;
    uint2 o;
    o.x = f2bu(p[0]) | (f2bu(p[1]) << 16);
    o.y = f2bu(p[2]) | (f2bu(p[3]) << 16);
    WP[idx] = o;
}

// =====================================================================
// Bidirectional batched GRU (proven in R3): one block = 4 mols x 1 dir,
// 960 threads. Phase 1: thread j computes gh row j for 4 mols from k-major
// packed bf16 Whh. Phase 2: gates + state update. h in LDS.
// =====================================================================
constexpr int GRU_G = 4;
constexpr int GRU_T = 960;

__global__ __launch_bounds__(GRU_T) void gru2_kernel(
    const bf16* __restrict__ gi_f, const bf16* __restrict__ gi_b,
    const uint2* __restrict__ WPf, const uint2* __restrict__ WPb,
    const float* __restrict__ bhh_f, const float* __restrict__ bhh_b,
    const float* __restrict__ h0, bf16* __restrict__ out)
{
    const int dir = blockIdx.x & 1;
    const int m0  = (blockIdx.x >> 1) * GRU_G;
    const uint2* WP  = dir ? WPb : WPf;
    const float* bhh = dir ? bhh_b : bhh_f;
    const bf16*  gi  = dir ? gi_b  : gi_f;

    __shared__ float Hs[GRU_G][304];
    __shared__ float GHs[GRU_G][904];
    const int tid = threadIdx.x;
    const bool rOK = tid < 900;
    const float bb = rOK ? bhh[tid] : 0.f;

    for (int idx = tid; idx < GRU_G * Hd; idx += GRU_T) {
        const int g = idx / Hd, hh = idx - g * Hd;
        Hs[g][hh] = h0[(long)(m0 + g) * Hd + hh];
    }
    __syncthreads();

    for (int t = 0; t < Aat; ++t) {
        if (rOK) {
            float acc[GRU_G] = {};
            const uint2* wp = WP + tid;
            #pragma unroll 2
            for (int k4 = 0; k4 < 75; ++k4) {
                const uint2 u = wp[k4 * 900];
                const float w0 = __uint_as_float(u.x << 16);
                const float w1 = __uint_as_float(u.x & 0xffff0000u);
                const float w2 = __uint_as_float(u.y << 16);
                const float w3 = __uint_as_float(u.y & 0xffff0000u);
                #pragma unroll
                for (int g = 0; g < GRU_G; ++g) {
                    const float4 hv = *(const float4*)&Hs[g][k4 * 4];
                    acc[g] = fmaf(w0, hv.x, acc[g]);
                    acc[g] = fmaf(w1, hv.y, acc[g]);
                    acc[g] = fmaf(w2, hv.z, acc[g]);
                    acc[g] = fmaf(w3, hv.w, acc[g]);
                }
            }
            #pragma unroll
            for (int g = 0; g < GRU_G; ++g) GHs[g][tid] = acc[g] + bb;
        }
        __syncthreads();
        const int a = dir ? (Aat - 1 - t) : t;
        for (int idx = tid; idx < GRU_G * Hd; idx += GRU_T) {
            const int g = idx / Hd, hh = idx - g * Hd;
            const long row = (long)(m0 + g) * Aat + a;
            const bf16* girow = gi + row * 900;
            const float ir  = b2f(girow[hh]);
            const float iz  = b2f(girow[300 + hh]);
            const float inn = b2f(girow[600 + hh]);
            const float hr = GHs[g][hh], hz = GHs[g][300 + hh], hn = GHs[g][600 + hh];
            const float rr = 1.f / (1.f + __expf(-(ir + hr)));
            const float zz = 1.f / (1.f + __expf(-(iz + hz)));
            float nin = inn + rr * hn;
            nin = fminf(fmaxf(nin, -15.f), 15.f);
            const float e2 = __expf(-2.f * nin);
            const float nn = (1.f - e2) / (1.f + e2);
            const float hnew = (1.f - zz) * nn + zz * Hs[g][hh];
            Hs[g][hh] = hnew;
            out[row * 600 + (long)dir * 300 + hh] = f2b(hnew);
        }
        __syncthreads();
    }
}

// =====================================================================
extern "C" void kernel_launch(void* const* d_in, const int* in_sizes, int n_in,
                              void* d_out, int out_size, void* d_ws, size_t ws_size,
                              hipStream_t stream)
{
    (void)in_sizes; (void)n_in; (void)out_size; (void)ws_size;

    const float* f_atoms  = (const float*)d_in[0];
    const float* f_bonds  = (const float*)d_in[1];
    const int*   a2b      = (const int*)d_in[2];
    const int*   b2a      = (const int*)d_in[3];
    const int*   b2revb   = (const int*)d_in[4];
    const float* W_i_atom = (const float*)d_in[7];
    const float* W_i_bond = (const float*)d_in[8];
    const float* W_h      = (const float*)d_in[9];    // [2,300,300]
    const float* lr_W     = (const float*)d_in[10];   // [300,900]
    const float* W_o_W    = (const float*)d_in[11];   // [300,600]
    const float* W_o_b    = (const float*)d_in[12];
    const float* gWih_f   = (const float*)d_in[13];
    const float* gWhh_f   = (const float*)d_in[14];
    const float* gbih_f   = (const float*)d_in[15];
    const float* gbhh_f   = (const float*)d_in[16];
    const float* gWih_b   = (const float*)d_in[17];
    const float* gWhh_b   = (const float*)d_in[18];
    const float* gbih_b   = (const float*)d_in[19];
    const float* gbhh_b   = (const float*)d_in[20];

    // ---- workspace: 4 regions, 235.9 MB peak (<= R2/R3's proven 236.5) ----
    const size_t F32A_B = (size_t)NP1 * Hd * 4;     // 39.32 MB
    const size_t BND_B  = (size_t)BP1 * Hd * 2;     // 78.64 MB
    const size_t GI_B   = (size_t)Nat * 900 * 2;    // 58.98 MB
    const size_t H0_B   = (size_t)Mmol * Hd * 4;    // 0.61 MB
    const size_t WP_B   = (size_t)75 * 900 * 8;     // 0.54 MB

    size_t off = 0;
    auto alloc = [&](size_t b) { size_t r = off; off += (b + 255) & ~(size_t)255; return r; };
    const size_t r1_o = alloc(F32A_B);   // IA [1-10] -> {H0,WPf,WPb} [11-14] -> AH [15-16]
    const size_t r2_o = alloc(F32A_B);   // MA [3-10] -> GRU [14-15]
    const size_t r3_o = alloc(BND_B);    // IB/MB1 [2-9] -> NODE [10-11] -> GIF [12-14]
    const size_t r4_o = alloc(BND_B);    // MB0 [5-7] -> AGG@0 [9-10], NRb@GI_B [10-13] -> GIB@0 [13-14]

    char* ws = (char*)d_ws;
    float* IA   = (float*)(ws + r1_o);
    float* H0p  = (float*)(ws + r1_o);
    uint2* WPf  = (uint2*)(ws + r1_o + ((H0_B + 255) & ~(size_t)255));
    uint2* WPb  = (uint2*)((char*)WPf + ((WP_B + 255) & ~(size_t)255));
    float* AH   = (float*)(ws + r1_o);
    float* MAb  = (float*)(ws + r2_o);
    bf16*  GRU  = (bf16*)(ws + r2_o);
    bf16*  IB   = (bf16*)(ws + r3_o);
    bf16*  MB1  = IB;                         // in-place over IB (same-elem same-thread)
    float* NODE = (float*)(ws + r3_o);
    bf16*  GIF  = (bf16*)(ws + r3_o);
    bf16*  MB0  = (bf16*)(ws + r4_o);
    float* AGG  = (float*)(ws + r4_o);
    bf16*  NRb  = (bf16*)(ws + r4_o + GI_B);  // 19.66 MB fits in 78.64-58.98
    bf16*  GIB  = (bf16*)(ws + r4_o);
    float* OUT  = (float*)d_out;

    const dim3 blk(256);
    auto grd = [](int n, int h) { return dim3((n + BMr - 1) / BMr, (h + BNc - 1) / BNc); };

    // 1. IA = relu(f_atoms @ W_i_atom^T) -> f32
    gemm_k<1, true, false, false, false, false><<<grd(NP1, Hd), blk, 0, stream>>>(
        f_atoms, nullptr, nullptr, nullptr, nullptr, W_i_atom, nullptr, nullptr,
        IA, nullptr, NP1, AF, Hd);
    // 2. IB = relu(f_bonds @ W_i_bond^T) -> bf16
    gemm_k<1, true, false, false, true, false><<<grd(BP1, Hd), blk, 0, stream>>>(
        f_bonds, nullptr, nullptr, nullptr, nullptr, W_i_bond, nullptr, nullptr,
        IB, nullptr, BP1, BFd, Hd);
    // 3. MA = IA + sum*max(IB gathered)
    agg_kernel<true><<<NP1, 320, 0, stream>>>(IB, a2b, IA, MAb, 0);
    // 4. MB0 = relu(IB + (MA[b2a]-IB[b2revb]) @ Wh0^T) -> bf16 (fused gather)
    gemm_k<3, true, false, true, true, false><<<grd(BP1, Hd), blk, 0, stream>>>(
        IB, MAb, nullptr, b2a, b2revb, W_h, nullptr, IB,
        MB0, nullptr, BP1, Hd, Hd);
    // 5. MA += sum*max(MB0 gathered)
    agg_kernel<true><<<NP1, 320, 0, stream>>>(MB0, a2b, MAb, MAb, 0);
    // 6. MB1(=IB in place) = relu(IB + (MA[b2a]-MB0[b2revb]) @ Wh1^T)
    gemm_k<3, true, false, true, true, false><<<grd(BP1, Hd), blk, 0, stream>>>(
        MB0, MAb, nullptr, b2a, b2revb, W_h + 300 * 300, nullptr, IB,
        MB1, nullptr, BP1, Hd, Hd);
    // 7. AGG = sum*max(MB1 gathered), atoms 1..N
    agg_kernel<false><<<Nat, 320, 0, stream>>>(MB1, a2b, nullptr, AGG, 1);
    // 8. node = concat(AGG, MA, IA) @ lr_W^T -> NODE f32 (pre-relu) + NRb bf16 (relu)
    gemm_k<4, false, false, false, false, true><<<grd(Nat, Hd), blk, 0, stream>>>(
        AGG, MAb + Hd, IA + Hd, nullptr, nullptr, lr_W, nullptr, nullptr,
        NODE, NRb, Nat, 900, Hd);
    // 9. h0 = per-mol max of pre-relu node (IA dead; H0 overlays r1)
    h0_kernel<<<Mmol, 320, 0, stream>>>(NODE, H0p);
    // 9b. pack Whh -> bf16 k-major (in r1 after IA dead)
    pack_whh<<<(75 * 900 + 255) / 256, 256, 0, stream>>>(gWhh_f, WPf);
    pack_whh<<<(75 * 900 + 255) / 256, 256, 0, stream>>>(gWhh_b, WPb);
    // 10/11. gi = NRb @ gWih^T + gbih -> bf16 [Nat,900]
    gemm_k<0, false, true, false, true, false><<<grd(Nat, 900), blk, 0, stream>>>(
        NRb, nullptr, nullptr, nullptr, nullptr, gWih_f, gbih_f, nullptr,
        GIF, nullptr, Nat, Hd, 900);
    gemm_k<0, false, true, false, true, false><<<grd(Nat, 900), blk, 0, stream>>>(
        NRb, nullptr, nullptr, nullptr, nullptr, gWih_b, gbih_b, nullptr,
        GIB, nullptr, Nat, Hd, 900);
    // 12. bidirectional GRU scan -> bf16 [Nat, 600]
    gru2_kernel<<<(Mmol / GRU_G) * 2, GRU_T, 0, stream>>>(
        GIF, GIB, WPf, WPb, gbhh_f, gbhh_b, H0p, GRU);
    // 13. AH = relu(GRU @ W_o_W^T + W_o_b) -> f32
    gemm_k<0, true, true, false, false, false><<<grd(Nat, Hd), blk, 0, stream>>>(
        GRU, nullptr, nullptr, nullptr, nullptr, W_o_W, W_o_b, nullptr,
        AH, nullptr, Nat, 600, Hd);
    // 14. mol_vecs = mean over atoms -> f32 d_out
    mean_kernel<<<Mmol, 320, 0, stream>>>(AH, OUT);
}

// Round 6
// 2997.012 us; speedup vs baseline: 4.7273x; 1.5670x over previous
//
#include <hip/hip_runtime.h>
#include <hip/hip_bf16.h>

using bf16 = __hip_bfloat16;
using uint = unsigned int;
typedef __attribute__((ext_vector_type(8))) short short8v;   // 8 x bf16 MFMA operand
typedef __attribute__((ext_vector_type(4))) float float4v;   // MFMA accumulator

__device__ __forceinline__ float b2f(bf16 x){ return __bfloat162float(x); }
__device__ __forceinline__ bf16  f2b(float x){ return __float2bfloat16(x); }
__device__ __forceinline__ uint f2bu(float x){            // bf16 bits, RNE
    uint u = __float_as_uint(x);
    return (u + 0x7fffu + ((u >> 16) & 1u)) >> 16;
}
__device__ __forceinline__ float blo(uint u){ return __uint_as_float(u << 16); }
__device__ __forceinline__ float bhi(uint u){ return __uint_as_float(u & 0xffff0000u); }

// ---------------- problem constants ----------------
constexpr int Mmol = 512, Aat = 64;
constexpr int Nat  = Mmol * Aat;      // 32768
constexpr int NP1  = Nat + 1;
constexpr int Bnd  = Nat * 4;         // 131072
constexpr int BP1  = Bnd + 1;
constexpr int Hd   = 300;
constexpr int AF   = 133, BFd = 147;
constexpr int NB   = 6;

// =====================================================================
// MFMA GEMM: C[n,h] = act( A[n,K] @ Wp[h,Kp]^T (+bias)(+res) ), bf16 MFMA
// 16x16x32. Block 256 = 4 waves; tile 128 rows x 64 cols; wave = 32 rows
// (2 m-frags) x 64 cols (4 n-frags). NO LDS: A and B fragments are direct
// global loads (16B/lane fully-used segments; W is L2-resident).
//   AM 0: A = bf16 row-major [n][K]
//   AM 3: A(r,k) = MAf[g1[r]][k] - MBh[g2[r]][k]  (f32/bf16 gather, K=300)
// Wp: pre-packed bf16, rows padded to grid cols, k padded to Kp (mult 32,
// zero-filled) -> B-frags never need masking. A tail-tile masked in regs.
// =====================================================================
template<int AM, bool RELU, bool BIAS, bool RES, bool OUTBF16, int TAILK>
__global__ __launch_bounds__(256) void mgemm(
    const bf16* __restrict__ Abh, const float* __restrict__ MAf, const bf16* __restrict__ MBh,
    const int* __restrict__ g1, const int* __restrict__ g2,
    const bf16* __restrict__ Wp, const float* __restrict__ bias, const bf16* __restrict__ res,
    void* __restrict__ Cp, int n, int K, int Kp, int h)
{
    const int tid  = threadIdx.x;
    const int lane = tid & 63, w = tid >> 6;
    const int l15  = lane & 15, quad = lane >> 4;
    const long rowBase = (long)blockIdx.y * 128;
    const long colBase = (long)blockIdx.x * 64;

    long arow[2], ga[2], gb[2];
    #pragma unroll
    for (int mt = 0; mt < 2; ++mt) {
        long r = rowBase + w * 32 + mt * 16 + l15;
        if (r >= n) r = n - 1;               // clamped rows: garbage acc, never stored
        arow[mt] = r;
        if constexpr (AM == 3) { ga[mt] = g1[r]; gb[mt] = g2[r]; }
        else { ga[mt] = 0; gb[mt] = 0; }
    }

    const bf16* wp0 = Wp + (colBase + l15) * (long)Kp + quad * 8;

    float4v acc[2][4];
    #pragma unroll
    for (int mt = 0; mt < 2; ++mt)
        #pragma unroll
        for (int nt = 0; nt < 4; ++nt)
            acc[mt][nt] = (float4v){0.f, 0.f, 0.f, 0.f};

    const int ktiles = (K + 31) / 32;
    for (int kt = 0; kt < ktiles; ++kt) {
        const int kb = kt * 32;
        const int koff = kb + quad * 8;
        short8v bfr[4];
        #pragma unroll
        for (int nt = 0; nt < 4; ++nt)
            bfr[nt] = *(const short8v*)(wp0 + (long)nt * 16 * Kp + kb);
        short8v af[2];
        if constexpr (AM == 0) {
            #pragma unroll
            for (int mt = 0; mt < 2; ++mt) {
                const bf16* p = Abh + arow[mt] * (long)K + koff;
                union { uint2 u2[2]; short8v s; } t;
                t.u2[0] = *(const uint2*)p;
                t.u2[1] = *(const uint2*)(p + 4);
                af[mt] = t.s;
            }
        } else {   // AM == 3 fused gather-sub
            #pragma unroll
            for (int mt = 0; mt < 2; ++mt) {
                const float* pa = MAf + ga[mt] * 300 + koff;
                const bf16*  pb = MBh + gb[mt] * 300 + koff;
                const float4 m0 = *(const float4*)pa;
                const float4 m1 = *(const float4*)(pa + 4);
                const uint2  u0 = *(const uint2*)pb;
                const uint2  u1 = *(const uint2*)(pb + 4);
                float v[8];
                v[0] = m0.x - blo(u0.x); v[1] = m0.y - bhi(u0.x);
                v[2] = m0.z - blo(u0.y); v[3] = m0.w - bhi(u0.y);
                v[4] = m1.x - blo(u1.x); v[5] = m1.y - bhi(u1.x);
                v[6] = m1.z - blo(u1.y); v[7] = m1.w - bhi(u1.y);
                short8v s;
                #pragma unroll
                for (int j = 0; j < 8; ++j) s[j] = (short)f2bu(v[j]);
                af[mt] = s;
            }
        }
        if constexpr (TAILK != 0) {
            if (kb + 32 > K) {               // uniform branch, last tile only
                #pragma unroll
                for (int j = 0; j < 8; ++j)
                    if (koff + j >= K) { af[0][j] = 0; af[1][j] = 0; }
            }
        }
        #pragma unroll
        for (int mt = 0; mt < 2; ++mt)
            #pragma unroll
            for (int nt = 0; nt < 4; ++nt)
                acc[mt][nt] = __builtin_amdgcn_mfma_f32_16x16x32_bf16(
                    af[mt], bfr[nt], acc[mt][nt], 0, 0, 0);
    }

    float biasv[4];
    #pragma unroll
    for (int nt = 0; nt < 4; ++nt) {
        const long c = colBase + nt * 16 + l15;
        biasv[nt] = (BIAS && c < h) ? bias[c] : 0.f;
    }
    #pragma unroll
    for (int mt = 0; mt < 2; ++mt) {
        #pragma unroll
        for (int reg = 0; reg < 4; ++reg) {
            const long r = rowBase + w * 32 + mt * 16 + quad * 4 + reg;
            if (r < n) {
                #pragma unroll
                for (int nt = 0; nt < 4; ++nt) {
                    const long c = colBase + nt * 16 + l15;
                    if (c < h) {
                        float v = acc[mt][nt][reg];
                        if constexpr (RES)  v += b2f(res[r * (long)h + c]);
                        if constexpr (BIAS) v += biasv[nt];
                        if constexpr (RELU) v = fmaxf(v, 0.f);
                        if constexpr (OUTBF16) ((bf16*)Cp)[r * (long)h + c] = f2b(v);
                        else                   ((float*)Cp)[r * (long)h + c] = v;
                    }
                }
            }
        }
    }
}

// =====================================================================
// generic f32->bf16 pack with row/k zero-padding: Wp[hp][Kp] <- W[h][K]
// =====================================================================
__global__ __launch_bounds__(256) void pack_w(const float* __restrict__ W, bf16* __restrict__ Wp,
                                              int h, int K, long total, int Kp)
{
    const long idx = (long)blockIdx.x * 256 + threadIdx.x;
    if (idx >= total) return;
    const long r = idx / Kp;
    const int kk = (int)(idx - r * Kp);
    Wp[idx] = (r < h && kk < K) ? f2b(W[r * (long)K + kk]) : f2b(0.f);
}

// =====================================================================
// f32 VALU GEMM (proven R5 path) for IA (k=133) and node (concat3, k=900)
//   AM 1: f32 A direct;  AM 4: concat3 f32 (AGG|MA|IA)
// DUAL: write Cp f32 (pre-relu) AND Cp2 bf16 (relu'd)
// =====================================================================
constexpr int BMr = 256, BNc = 64;

template<int AMODE, bool RELU, bool OUTBF16, bool DUAL>
__global__ __launch_bounds__(256) void gemm_k(
    const void* __restrict__ A, const float* __restrict__ A2, const float* __restrict__ A3,
    const float* __restrict__ W,
    void* __restrict__ Cp, bf16* __restrict__ Cp2, int n, int k, int h)
{
    __shared__ float As[16][BMr];
    __shared__ float Ws[16][BNc];

    const int tid = threadIdx.x;
    const int tx = tid & 7, ty = tid >> 3;
    const long rowBase = (long)blockIdx.x * BMr;
    const long colBase = (long)blockIdx.y * BNc;

    const long grow = rowBase + tid;
    const bool rv = grow < n;
    const int wcol = tid & 63, kq = tid >> 6;
    const long gcol = colBase + wcol;
    const bool cvv = gcol < h;

    float acc[8][8] = {};

    const int ktiles = (k + 15) / 16;
    for (int kt = 0; kt < ktiles; ++kt) {
        const int kb = kt * 16;
        __syncthreads();
        if constexpr (AMODE == 1) {
            const float* ap = (const float*)A + grow * (long)k + kb;
            #pragma unroll
            for (int c = 0; c < 16; ++c)
                As[c][tid] = (rv && kb + c < k) ? ap[c] : 0.f;
        } else {  // AMODE 4
            #pragma unroll
            for (int c = 0; c < 16; ++c) {
                const int kk = kb + c;
                float v = 0.f;
                if (rv && kk < k) {
                    v = (kk < 300) ? ((const float*)A)[grow * 300 + kk]
                      : (kk < 600) ? A2[grow * 300 + (kk - 300)]
                                   : A3[grow * 300 + (kk - 600)];
                }
                As[c][tid] = v;
            }
        }
        #pragma unroll
        for (int c = 0; c < 4; ++c) {
            const int kk = kb + kq * 4 + c;
            Ws[kq * 4 + c][wcol] = (cvv && kk < k) ? W[gcol * (long)k + kk] : 0.f;
        }
        __syncthreads();
        #pragma unroll
        for (int kk = 0; kk < 16; ++kk) {
            const float4 a0 = *(const float4*)&As[kk][ty * 8];
            const float4 a1 = *(const float4*)&As[kk][ty * 8 + 4];
            const float4 b0 = *(const float4*)&Ws[kk][tx * 8];
            const float4 b1 = *(const float4*)&Ws[kk][tx * 8 + 4];
            const float aa[8] = {a0.x,a0.y,a0.z,a0.w,a1.x,a1.y,a1.z,a1.w};
            const float bb[8] = {b0.x,b0.y,b0.z,b0.w,b1.x,b1.y,b1.z,b1.w};
            #pragma unroll
            for (int i = 0; i < 8; ++i)
                #pragma unroll
                for (int j = 0; j < 8; ++j)
                    acc[i][j] = fmaf(aa[i], bb[j], acc[i][j]);
        }
    }
    #pragma unroll
    for (int i = 0; i < 8; ++i) {
        const long r = rowBase + ty * 8 + i;
        if (r < n) {
            #pragma unroll
            for (int j = 0; j < 8; ++j) {
                const long c = colBase + tx * 8 + j;
                if (c < h) {
                    float v = acc[i][j];
                    if constexpr (RELU) v = fmaxf(v, 0.f);
                    if constexpr (DUAL) {
                        ((float*)Cp)[r * (long)h + c] = v;
                        Cp2[r * (long)h + c] = f2b(fmaxf(v, 0.f));
                    } else if constexpr (OUTBF16) {
                        ((bf16*)Cp)[r * (long)h + c] = f2b(v);
                    } else {
                        ((float*)Cp)[r * (long)h + c] = v;
                    }
                }
            }
        }
    }
}

// =====================================================================
template<bool ADD>
__global__ __launch_bounds__(320) void agg_kernel(
    const bf16* __restrict__ MB, const int* __restrict__ a2b,
    const float* __restrict__ src, float* __restrict__ out, int rowoff)
{
    const int hh = threadIdx.x;
    if (hh >= Hd) return;
    const long atom = (long)blockIdx.x + rowoff;
    const int* nb = a2b + atom * NB;
    float s = 0.f, mx = -1e30f;
    #pragma unroll
    for (int j = 0; j < NB; ++j) {
        const float v = b2f(MB[(long)nb[j] * Hd + hh]);
        s += v; mx = fmaxf(mx, v);
    }
    const float agg = s * mx;
    const long o = (long)blockIdx.x * Hd + hh;
    if constexpr (ADD) out[o] = src[atom * Hd + hh] + agg;
    else               out[o] = agg;
}

__global__ __launch_bounds__(320) void h0_kernel(const float* __restrict__ node, float* __restrict__ h0)
{
    const int hh = threadIdx.x;
    if (hh >= Hd) return;
    const long m = blockIdx.x;
    float mx = -1e30f;
    for (int a = 0; a < Aat; ++a)
        mx = fmaxf(mx, node[(m * Aat + a) * (long)Hd + hh]);
    h0[m * Hd + hh] = mx;
}

__global__ __launch_bounds__(320) void mean_kernel(const float* __restrict__ AH, float* __restrict__ out)
{
    const int hh = threadIdx.x;
    if (hh >= Hd) return;
    const long m = blockIdx.x;
    float s = 0.f;
    for (int a = 0; a < Aat; ++a)
        s += AH[(m * Aat + a) * (long)Hd + hh];
    out[m * Hd + hh] = s * (1.f / 64.f);
}

__global__ __launch_bounds__(256) void pack_whh(const float* __restrict__ W, uint2* __restrict__ WP)
{
    const int idx = blockIdx.x * 256 + threadIdx.x;
    if (idx >= 75 * 900) return;
    const int k4 = idx / 900, r = idx - k4 * 900;
    const float* p = W + (long)r * 300 + k4 * 4;
    uint2 o;
    o.x = f2bu(p[0]) | (f2bu(p[1]) << 16);
    o.y = f2bu(p[2]) | (f2bu(p[3]) << 16);
    WP[idx] = o;
}

// ===================================================================== GRU
constexpr int GRU_G = 4;
constexpr int GRU_T = 960;

__global__ __launch_bounds__(GRU_T) void gru2_kernel(
    const bf16* __restrict__ gi_f, const bf16* __restrict__ gi_b,
    const uint2* __restrict__ WPf, const uint2* __restrict__ WPb,
    const float* __restrict__ bhh_f, const float* __restrict__ bhh_b,
    const float* __restrict__ h0, bf16* __restrict__ out)
{
    const int dir = blockIdx.x & 1;
    const int m0  = (blockIdx.x >> 1) * GRU_G;
    const uint2* WP  = dir ? WPb : WPf;
    const float* bhh = dir ? bhh_b : bhh_f;
    const bf16*  gi  = dir ? gi_b  : gi_f;

    __shared__ float Hs[GRU_G][304];
    __shared__ float GHs[GRU_G][904];
    const int tid = threadIdx.x;
    const bool rOK = tid < 900;
    const float bb = rOK ? bhh[tid] : 0.f;

    for (int idx = tid; idx < GRU_G * Hd; idx += GRU_T) {
        const int g = idx / Hd, hh = idx - g * Hd;
        Hs[g][hh] = h0[(long)(m0 + g) * Hd + hh];
    }
    __syncthreads();

    for (int t = 0; t < Aat; ++t) {
        if (rOK) {
            float acc[GRU_G] = {};
            const uint2* wp = WP + tid;
            #pragma unroll 2
            for (int k4 = 0; k4 < 75; ++k4) {
                const uint2 u = wp[k4 * 900];
                const float w0 = blo(u.x), w1 = bhi(u.x), w2 = blo(u.y), w3 = bhi(u.y);
                #pragma unroll
                for (int g = 0; g < GRU_G; ++g) {
                    const float4 hv = *(const float4*)&Hs[g][k4 * 4];
                    acc[g] = fmaf(w0, hv.x, acc[g]);
                    acc[g] = fmaf(w1, hv.y, acc[g]);
                    acc[g] = fmaf(w2, hv.z, acc[g]);
                    acc[g] = fmaf(w3, hv.w, acc[g]);
                }
            }
            #pragma unroll
            for (int g = 0; g < GRU_G; ++g) GHs[g][tid] = acc[g] + bb;
        }
        __syncthreads();
        const int a = dir ? (Aat - 1 - t) : t;
        for (int idx = tid; idx < GRU_G * Hd; idx += GRU_T) {
            const int g = idx / Hd, hh = idx - g * Hd;
            const long row = (long)(m0 + g) * Aat + a;
            const bf16* girow = gi + row * 900;
            const float ir  = b2f(girow[hh]);
            const float iz  = b2f(girow[300 + hh]);
            const float inn = b2f(girow[600 + hh]);
            const float hr = GHs[g][hh], hz = GHs[g][300 + hh], hn = GHs[g][600 + hh];
            const float rr = 1.f / (1.f + __expf(-(ir + hr)));
            const float zz = 1.f / (1.f + __expf(-(iz + hz)));
            float nin = inn + rr * hn;
            nin = fminf(fmaxf(nin, -15.f), 15.f);
            const float e2 = __expf(-2.f * nin);
            const float nn = (1.f - e2) / (1.f + e2);
            const float hnew = (1.f - zz) * nn + zz * Hs[g][hh];
            Hs[g][hh] = hnew;
            out[row * 600 + (long)dir * 300 + hh] = f2b(hnew);
        }
        __syncthreads();
    }
}

// =====================================================================
extern "C" void kernel_launch(void* const* d_in, const int* in_sizes, int n_in,
                              void* d_out, int out_size, void* d_ws, size_t ws_size,
                              hipStream_t stream)
{
    (void)in_sizes; (void)n_in; (void)out_size; (void)ws_size;

    const float* f_atoms  = (const float*)d_in[0];
    const float* f_bonds  = (const float*)d_in[1];
    const int*   a2b      = (const int*)d_in[2];
    const int*   b2a      = (const int*)d_in[3];
    const int*   b2revb   = (const int*)d_in[4];
    const float* W_i_atom = (const float*)d_in[7];
    const float* W_i_bond = (const float*)d_in[8];
    const float* W_h      = (const float*)d_in[9];
    const float* lr_W     = (const float*)d_in[10];
    const float* W_o_W    = (const float*)d_in[11];
    const float* W_o_b    = (const float*)d_in[12];
    const float* gWih_f   = (const float*)d_in[13];
    const float* gWhh_f   = (const float*)d_in[14];
    const float* gbih_f   = (const float*)d_in[15];
    const float* gbhh_f   = (const float*)d_in[16];
    const float* gWih_b   = (const float*)d_in[17];
    const float* gWhh_b   = (const float*)d_in[18];
    const float* gbih_b   = (const float*)d_in[19];
    const float* gbhh_b   = (const float*)d_in[20];

    // ---- workspace: identical footprint to proven R5 (235.9 MB) + 4KB guard ----
    const size_t F32A_B = (size_t)NP1 * Hd * 4;
    const size_t BND_B  = (size_t)BP1 * Hd * 2;
    const size_t GI_B   = (size_t)Nat * 900 * 2;    // 58.98 MB
    const size_t H0_B   = (size_t)Mmol * Hd * 4;
    const size_t WP_B   = (size_t)75 * 900 * 8;

    size_t off = 0;
    auto alloc = [&](size_t b) { size_t r = off; off += (b + 255) & ~(size_t)255; return r; };
    const size_t r1_o = alloc(F32A_B);   // IA [1-8] -> {H0,WPgru} [9-12] -> AH [13-14]
    const size_t r2_o = alloc(F32A_B);   // MA [3-8] -> GRU [12-13]
    const size_t r3_o = alloc(BND_B);    // IB/MB1 [2-7] -> NODE [8-9] -> GIF [10-12]
    const size_t r4_o = alloc(BND_B + 4096); // FB16 [1-2] -> MB0 [4-6] -> AGG@0 + NRb@GI_B -> GIB@0
                                             // +4KB guard for tail-tile overreads

    char* ws = (char*)d_ws;
    float* IA   = (float*)(ws + r1_o);
    float* H0p  = (float*)(ws + r1_o);
    uint2* WPf  = (uint2*)(ws + r1_o + ((H0_B + 255) & ~(size_t)255));
    uint2* WPb  = (uint2*)((char*)WPf + ((WP_B + 255) & ~(size_t)255));
    float* AH   = (float*)(ws + r1_o);
    float* MAb  = (float*)(ws + r2_o);
    bf16*  GRU  = (bf16*)(ws + r2_o);
    bf16*  IB   = (bf16*)(ws + r3_o);
    bf16*  MB1  = IB;
    float* NODE = (float*)(ws + r3_o);
    bf16*  GIF  = (bf16*)(ws + r3_o);
    bf16*  FB16 = (bf16*)(ws + r4_o);
    bf16*  MB0  = (bf16*)(ws + r4_o);
    float* AGG  = (float*)(ws + r4_o);
    bf16*  NRb  = (bf16*)(ws + r4_o + GI_B);
    bf16*  GIB  = (bf16*)(ws + r4_o);
    float* OUT  = (float*)d_out;
    bf16*  WSC  = (bf16*)d_out;        // 614400 B: time-shared packed-weight scratch

    const dim3 blk(256);
    auto grdF = [](int n, int h) { return dim3((n + BMr - 1) / BMr, (h + BNc - 1) / BNc); };
    auto grdM = [](int n, int h) { return dim3((h + 63) / 64, (n + 127) / 128); };
    auto pk = [&](const float* W, bf16* Wp, int h, int K, long hp, int Kp) {
        const long tot = hp * Kp;
        pack_w<<<dim3((tot + 255) / 256), blk, 0, stream>>>(W, Wp, h, K, tot, Kp);
    };

    // 1. IA = relu(f_atoms @ W_i_atom^T) -> f32 (VALU path, k=133)
    gemm_k<1, true, false, false><<<grdF(NP1, Hd), blk, 0, stream>>>(
        f_atoms, nullptr, nullptr, W_i_atom, IA, nullptr, NP1, AF, Hd);
    // 1b. pack f_bonds -> bf16 [BP1][160] ; pack W_i_bond -> [320][160] @d_out
    pk(f_bonds, FB16, BP1, BFd, BP1, 160);
    pk(W_i_bond, WSC, Hd, BFd, 320, 160);
    // 2. IB = relu(FB16 @ WIB^T)   [MFMA, K=160 no tail]
    mgemm<0, true, false, false, true, 0><<<grdM(BP1, Hd), blk, 0, stream>>>(
        FB16, nullptr, nullptr, nullptr, nullptr, WSC, nullptr, nullptr,
        IB, BP1, 160, 160, Hd);
    // 3. MA = IA + sum*max(IB gathered)
    agg_kernel<true><<<NP1, 320, 0, stream>>>(IB, a2b, IA, MAb, 0);
    // 3b. pack W_h[0] -> [320][320] @d_out
    pk(W_h, WSC, Hd, Hd, 320, 320);
    // 4. MB0 = relu(IB + (MA[b2a]-IB[b2revb]) @ Wh0^T)   [MFMA fused gather]
    mgemm<3, true, false, true, true, 12><<<grdM(BP1, Hd), blk, 0, stream>>>(
        nullptr, MAb, IB, b2a, b2revb, WSC, nullptr, IB,
        MB0, BP1, Hd, 320, Hd);
    // 5. MA += sum*max(MB0 gathered)
    agg_kernel<true><<<NP1, 320, 0, stream>>>(MB0, a2b, MAb, MAb, 0);
    // 5b. pack W_h[1]
    pk(W_h + 300 * 300, WSC, Hd, Hd, 320, 320);
    // 6. MB1(=IB) = relu(IB + (MA[b2a]-MB0[b2revb]) @ Wh1^T)
    mgemm<3, true, false, true, true, 12><<<grdM(BP1, Hd), blk, 0, stream>>>(
        nullptr, MAb, MB0, b2a, b2revb, WSC, nullptr, IB,
        MB1, BP1, Hd, 320, Hd);
    // 7. AGG = sum*max(MB1 gathered), atoms 1..N
    agg_kernel<false><<<Nat, 320, 0, stream>>>(MB1, a2b, nullptr, AGG, 1);
    // 8. node = concat(AGG, MA, IA) @ lr_W^T -> NODE f32 + NRb bf16 (relu)
    gemm_k<4, false, false, true><<<grdF(Nat, Hd), blk, 0, stream>>>(
        AGG, MAb + Hd, IA + Hd, lr_W, NODE, NRb, Nat, 900, Hd);
    // 9. h0 + GRU weight packs (r1: IA dead)
    h0_kernel<<<Mmol, 320, 0, stream>>>(NODE, H0p);
    pack_whh<<<(75 * 900 + 255) / 256, blk, 0, stream>>>(gWhh_f, WPf);
    pack_whh<<<(75 * 900 + 255) / 256, blk, 0, stream>>>(gWhh_b, WPb);
    // 10. GIF = NRb @ gWih_f^T + gbih_f   [MFMA, K=300 tail 12]
    pk(gWih_f, WSC, 900, Hd, 960, 320);          // 960*320*2 B == d_out size exactly
    mgemm<0, false, true, false, true, 12><<<grdM(Nat, 900), blk, 0, stream>>>(
        NRb, nullptr, nullptr, nullptr, nullptr, WSC, gbih_f, nullptr,
        GIF, Nat, Hd, 320, 900);
    // 11. GIB likewise
    pk(gWih_b, WSC, 900, Hd, 960, 320);
    mgemm<0, false, true, false, true, 12><<<grdM(Nat, 900), blk, 0, stream>>>(
        NRb, nullptr, nullptr, nullptr, nullptr, WSC, gbih_b, nullptr,
        GIB, Nat, Hd, 320, 900);
    // 12. bidirectional GRU scan
    gru2_kernel<<<(Mmol / GRU_G) * 2, GRU_T, 0, stream>>>(
        GIF, GIB, WPf, WPb, gbhh_f, gbhh_b, H0p, GRU);
    // 13. AH = relu(GRU @ W_o_W^T + W_o_b)   [MFMA, K=600 tail 24]
    pk(W_o_W, WSC, Hd, 600, 320, 608);
    mgemm<0, true, true, false, false, 24><<<grdM(Nat, Hd), blk, 0, stream>>>(
        GRU, nullptr, nullptr, nullptr, nullptr, WSC, W_o_b, nullptr,
        AH, Nat, 600, 608, Hd);
    // 14. mol_vecs = mean -> d_out (WOU scratch dead)
    mean_kernel<<<Mmol, 320, 0, stream>>>(AH, OUT);
}

// Round 7
// 2927.757 us; speedup vs baseline: 4.8391x; 1.0237x over previous
//
#include <hip/hip_runtime.h>
#include <hip/hip_bf16.h>

using bf16 = __hip_bfloat16;
using uint = unsigned int;
typedef __attribute__((ext_vector_type(8))) short short8v;   // 8 x bf16 MFMA operand
typedef __attribute__((ext_vector_type(4))) float float4v;   // MFMA accumulator

__device__ __forceinline__ float b2f(bf16 x){ return __bfloat162float(x); }
__device__ __forceinline__ bf16  f2b(float x){ return __float2bfloat16(x); }
__device__ __forceinline__ uint f2bu(float x){            // bf16 bits, RNE
    uint u = __float_as_uint(x);
    return (u + 0x7fffu + ((u >> 16) & 1u)) >> 16;
}
__device__ __forceinline__ float blo(uint u){ return __uint_as_float(u << 16); }
__device__ __forceinline__ float bhi(uint u){ return __uint_as_float(u & 0xffff0000u); }

// ---------------- problem constants ----------------
constexpr int Mmol = 512, Aat = 64;
constexpr int Nat  = Mmol * Aat;      // 32768
constexpr int NP1  = Nat + 1;
constexpr int Bnd  = Nat * 4;         // 131072
constexpr int BP1  = Bnd + 1;
constexpr int Hd   = 300;
constexpr int AF   = 133, BFd = 147;
constexpr int NB   = 6;

// =====================================================================
// MFMA GEMM (proven R6): C[n,h] = act( A[n,K] @ Wp[h,Kp]^T (+bias)(+res) )
// 16x16x32 bf16; block 256 = 4 waves; tile 128 rows x 64 cols; no LDS.
//   AM 0: A = bf16 row-major [n][K] (uint2 8B loads: rows only 4B-aligned)
//   AM 3: A(r,k) = MAf[g1[r]][k] - MBh[g2[r]][k]  (fused gather, K=300)
// DUAL: write Cp f32 (pre-relu) AND Cp2 bf16 (relu'd)
// =====================================================================
template<int AM, bool RELU, bool BIAS, bool RES, bool OUTBF16, bool DUAL, int TAILK>
__global__ __launch_bounds__(256) void mgemm(
    const bf16* __restrict__ Abh, const float* __restrict__ MAf, const bf16* __restrict__ MBh,
    const int* __restrict__ g1, const int* __restrict__ g2,
    const bf16* __restrict__ Wp, const float* __restrict__ bias, const bf16* __restrict__ res,
    void* __restrict__ Cp, bf16* __restrict__ Cp2, int n, int K, int Kp, int h)
{
    const int tid  = threadIdx.x;
    const int lane = tid & 63, w = tid >> 6;
    const int l15  = lane & 15, quad = lane >> 4;
    const long rowBase = (long)blockIdx.y * 128;
    const long colBase = (long)blockIdx.x * 64;

    long arow[2], ga[2], gb[2];
    #pragma unroll
    for (int mt = 0; mt < 2; ++mt) {
        long r = rowBase + w * 32 + mt * 16 + l15;
        if (r >= n) r = n - 1;               // clamped rows: garbage acc, never stored
        arow[mt] = r;
        if constexpr (AM == 3) { ga[mt] = g1[r]; gb[mt] = g2[r]; }
        else { ga[mt] = 0; gb[mt] = 0; }
    }

    const bf16* wp0 = Wp + (colBase + l15) * (long)Kp + quad * 8;

    float4v acc[2][4];
    #pragma unroll
    for (int mt = 0; mt < 2; ++mt)
        #pragma unroll
        for (int nt = 0; nt < 4; ++nt)
            acc[mt][nt] = (float4v){0.f, 0.f, 0.f, 0.f};

    const int ktiles = (K + 31) / 32;
    for (int kt = 0; kt < ktiles; ++kt) {
        const int kb = kt * 32;
        const int koff = kb + quad * 8;
        short8v bfr[4];
        #pragma unroll
        for (int nt = 0; nt < 4; ++nt)
            bfr[nt] = *(const short8v*)(wp0 + (long)nt * 16 * Kp + kb);
        short8v af[2];
        if constexpr (AM == 0) {
            #pragma unroll
            for (int mt = 0; mt < 2; ++mt) {
                const bf16* p = Abh + arow[mt] * (long)K + koff;
                union { uint2 u2[2]; short8v s; } t;
                t.u2[0] = *(const uint2*)p;
                t.u2[1] = *(const uint2*)(p + 4);
                af[mt] = t.s;
            }
        } else {   // AM == 3 fused gather-sub
            #pragma unroll
            for (int mt = 0; mt < 2; ++mt) {
                const float* pa = MAf + ga[mt] * 300 + koff;
                const bf16*  pb = MBh + gb[mt] * 300 + koff;
                const float4 m0 = *(const float4*)pa;
                const float4 m1 = *(const float4*)(pa + 4);
                const uint2  u0 = *(const uint2*)pb;
                const uint2  u1 = *(const uint2*)(pb + 4);
                float v[8];
                v[0] = m0.x - blo(u0.x); v[1] = m0.y - bhi(u0.x);
                v[2] = m0.z - blo(u0.y); v[3] = m0.w - bhi(u0.y);
                v[4] = m1.x - blo(u1.x); v[5] = m1.y - bhi(u1.x);
                v[6] = m1.z - blo(u1.y); v[7] = m1.w - bhi(u1.y);
                short8v s;
                #pragma unroll
                for (int j = 0; j < 8; ++j) s[j] = (short)f2bu(v[j]);
                af[mt] = s;
            }
        }
        if constexpr (TAILK != 0) {
            if (kb + 32 > K) {               // uniform branch, last tile only
                #pragma unroll
                for (int j = 0; j < 8; ++j)
                    if (koff + j >= K) { af[0][j] = 0; af[1][j] = 0; }
            }
        }
        #pragma unroll
        for (int mt = 0; mt < 2; ++mt)
            #pragma unroll
            for (int nt = 0; nt < 4; ++nt)
                acc[mt][nt] = __builtin_amdgcn_mfma_f32_16x16x32_bf16(
                    af[mt], bfr[nt], acc[mt][nt], 0, 0, 0);
    }

    float biasv[4];
    #pragma unroll
    for (int nt = 0; nt < 4; ++nt) {
        const long c = colBase + nt * 16 + l15;
        biasv[nt] = (BIAS && c < h) ? bias[c] : 0.f;
    }
    #pragma unroll
    for (int mt = 0; mt < 2; ++mt) {
        #pragma unroll
        for (int reg = 0; reg < 4; ++reg) {
            const long r = rowBase + w * 32 + mt * 16 + quad * 4 + reg;
            if (r < n) {
                #pragma unroll
                for (int nt = 0; nt < 4; ++nt) {
                    const long c = colBase + nt * 16 + l15;
                    if (c < h) {
                        float v = acc[mt][nt][reg];
                        if constexpr (RES)  v += b2f(res[r * (long)h + c]);
                        if constexpr (BIAS) v += biasv[nt];
                        if constexpr (RELU) v = fmaxf(v, 0.f);
                        if constexpr (DUAL) {
                            ((float*)Cp)[r * (long)h + c] = v;
                            Cp2[r * (long)h + c] = f2b(fmaxf(v, 0.f));
                        } else if constexpr (OUTBF16) {
                            ((bf16*)Cp)[r * (long)h + c] = f2b(v);
                        } else {
                            ((float*)Cp)[r * (long)h + c] = v;
                        }
                    }
                }
            }
        }
    }
}

// =====================================================================
// generic f32->bf16 pack with row/k zero-padding: Wp[hp][Kp] <- W[h][K]
// =====================================================================
__global__ __launch_bounds__(256) void pack_w(const float* __restrict__ W, bf16* __restrict__ Wp,
                                              int h, int K, long total, int Kp)
{
    const long idx = (long)blockIdx.x * 256 + threadIdx.x;
    if (idx >= total) return;
    const long r = idx / Kp;
    const int kk = (int)(idx - r * Kp);
    Wp[idx] = (r < h && kk < K) ? f2b(W[r * (long)K + kk]) : f2b(0.f);
}

// lr_W [300][900] -> Wp [320][960] bf16, segment-padded (3 x 300->320)
__global__ __launch_bounds__(256) void pack_lrw(const float* __restrict__ W, bf16* __restrict__ Wp)
{
    const int idx = blockIdx.x * 256 + threadIdx.x;
    if (idx >= 320 * 960) return;
    const int r = idx / 960, c = idx - r * 960;
    const int seg = c / 320, kk = c - seg * 320;
    Wp[idx] = (r < 300 && kk < 300) ? f2b(W[r * 900 + seg * 300 + kk]) : f2b(0.f);
}

// =====================================================================
// f32 VALU GEMM (IA only, k=133; keeps f_atoms at full precision)
// =====================================================================
constexpr int BMr = 256, BNc = 64;

__global__ __launch_bounds__(256) void gemm_ia(
    const float* __restrict__ A, const float* __restrict__ W,
    float* __restrict__ Cp, int n, int k, int h)
{
    __shared__ float As[16][BMr];
    __shared__ float Ws[16][BNc];

    const int tid = threadIdx.x;
    const int tx = tid & 7, ty = tid >> 3;
    const long rowBase = (long)blockIdx.x * BMr;
    const long colBase = (long)blockIdx.y * BNc;

    const long grow = rowBase + tid;
    const bool rv = grow < n;
    const int wcol = tid & 63, kq = tid >> 6;
    const long gcol = colBase + wcol;
    const bool cvv = gcol < h;

    float acc[8][8] = {};

    const int ktiles = (k + 15) / 16;
    for (int kt = 0; kt < ktiles; ++kt) {
        const int kb = kt * 16;
        __syncthreads();
        const float* ap = A + grow * (long)k + kb;
        #pragma unroll
        for (int c = 0; c < 16; ++c)
            As[c][tid] = (rv && kb + c < k) ? ap[c] : 0.f;
        #pragma unroll
        for (int c = 0; c < 4; ++c) {
            const int kk = kb + kq * 4 + c;
            Ws[kq * 4 + c][wcol] = (cvv && kk < k) ? W[gcol * (long)k + kk] : 0.f;
        }
        __syncthreads();
        #pragma unroll
        for (int kk = 0; kk < 16; ++kk) {
            const float4 a0 = *(const float4*)&As[kk][ty * 8];
            const float4 a1 = *(const float4*)&As[kk][ty * 8 + 4];
            const float4 b0 = *(const float4*)&Ws[kk][tx * 8];
            const float4 b1 = *(const float4*)&Ws[kk][tx * 8 + 4];
            const float aa[8] = {a0.x,a0.y,a0.z,a0.w,a1.x,a1.y,a1.z,a1.w};
            const float bb[8] = {b0.x,b0.y,b0.z,b0.w,b1.x,b1.y,b1.z,b1.w};
            #pragma unroll
            for (int i = 0; i < 8; ++i)
                #pragma unroll
                for (int j = 0; j < 8; ++j)
                    acc[i][j] = fmaf(aa[i], bb[j], acc[i][j]);
        }
    }
    #pragma unroll
    for (int i = 0; i < 8; ++i) {
        const long r = rowBase + ty * 8 + i;
        if (r < n) {
            #pragma unroll
            for (int j = 0; j < 8; ++j) {
                const long c = colBase + tx * 8 + j;
                if (c < h) Cp[r * (long)h + c] = fmaxf(acc[i][j], 0.f);
            }
        }
    }
}

// =====================================================================
template<bool ADD>
__global__ __launch_bounds__(320) void agg_kernel(
    const bf16* __restrict__ MB, const int* __restrict__ a2b,
    const float* __restrict__ src, float* __restrict__ out, int rowoff)
{
    const int hh = threadIdx.x;
    if (hh >= Hd) return;
    const long atom = (long)blockIdx.x + rowoff;
    const int* nb = a2b + atom * NB;
    float s = 0.f, mx = -1e30f;
    #pragma unroll
    for (int j = 0; j < NB; ++j) {
        const float v = b2f(MB[(long)nb[j] * Hd + hh]);
        s += v; mx = fmaxf(mx, v);
    }
    const float agg = s * mx;
    const long o = (long)blockIdx.x * Hd + hh;
    if constexpr (ADD) out[o] = src[atom * Hd + hh] + agg;
    else               out[o] = agg;
}

// cc_build: CC[r][0:300)=sum*max(MB1 gather), [320:620)=MA, [640:940)=IA, pads 0
__global__ __launch_bounds__(320) void cc_build(
    const bf16* __restrict__ MB, const int* __restrict__ a2b,
    const float* __restrict__ MA, const float* __restrict__ IA,
    bf16* __restrict__ CC)
{
    const int hh = threadIdx.x;
    const long r = blockIdx.x;          // 0..Nat-1, atom = r+1
    bf16* cr = CC + r * 960;
    if (hh < Hd) {
        const long atom = r + 1;
        const int* nb = a2b + atom * NB;
        float s = 0.f, mx = -1e30f;
        #pragma unroll
        for (int j = 0; j < NB; ++j) {
            const float v = b2f(MB[(long)nb[j] * Hd + hh]);
            s += v; mx = fmaxf(mx, v);
        }
        cr[hh]       = f2b(s * mx);
        cr[320 + hh] = f2b(MA[atom * Hd + hh]);
        cr[640 + hh] = f2b(IA[atom * Hd + hh]);
    } else {
        const int p = hh - Hd;          // 0..19
        cr[300 + p] = f2b(0.f);
        cr[620 + p] = f2b(0.f);
        cr[940 + p] = f2b(0.f);
    }
}

__global__ __launch_bounds__(320) void h0_kernel(const float* __restrict__ node, float* __restrict__ h0)
{
    const int hh = threadIdx.x;
    if (hh >= Hd) return;
    const long m = blockIdx.x;
    float mx = -1e30f;
    for (int a = 0; a < Aat; ++a)
        mx = fmaxf(mx, node[(m * Aat + a) * (long)Hd + hh]);
    h0[m * Hd + hh] = mx;
}

__global__ __launch_bounds__(320) void mean_kernel(const float* __restrict__ AH, float* __restrict__ out)
{
    const int hh = threadIdx.x;
    if (hh >= Hd) return;
    const long m = blockIdx.x;
    float s = 0.f;
    for (int a = 0; a < Aat; ++a)
        s += AH[(m * Aat + a) * (long)Hd + hh];
    out[m * Hd + hh] = s * (1.f / 64.f);
}

// =====================================================================
// MFMA GRU: one block = 16 mols x 1 dir (grid 64, 256 thr = 4 waves).
// Per step: GH[912][16] = WhhP[912][320] @ Hb[320][16] via mfma 16x16x32
// (A: m=l15 over Whh rows, B: n=l15 over mols — R6-proven operand pattern),
// then gates in f32 from LDS. h master stays f32; bf16 only on matmul input.
// =====================================================================
constexpr int GG = 16;

__global__ __launch_bounds__(256) void gru3_kernel(
    const bf16* __restrict__ gi_f, const bf16* __restrict__ gi_b,
    const bf16* __restrict__ WPf, const bf16* __restrict__ WPb,   // [912][320]
    const float* __restrict__ bhh_f, const float* __restrict__ bhh_b,
    const float* __restrict__ h0, bf16* __restrict__ out)
{
    const int dir = blockIdx.x & 1;
    const int m0  = (blockIdx.x >> 1) * GG;
    const bf16*  WP  = dir ? WPb : WPf;
    const float* bhh = dir ? bhh_b : bhh_f;
    const bf16*  gi  = dir ? gi_b  : gi_f;

    __shared__ float Hsf[GG][304];     // f32 master h
    __shared__ short Hsb[GG][328];     // bf16 mirror for B-frags (rows 16B-aligned)
    __shared__ float GHs[GG][916];     // gh, [mol][row]

    const int tid  = threadIdx.x;
    const int lane = tid & 63, w = tid >> 6;
    const int l15  = lane & 15, quad = lane >> 4;

    for (int idx = tid; idx < GG * 328; idx += 256) {
        const int g = idx / 328, hh = idx - g * 328;
        const float v = (hh < Hd) ? h0[(long)(m0 + g) * Hd + hh] : 0.f;
        if (hh < 304) Hsf[g][hh] = v;
        Hsb[g][hh] = (short)f2bu(v);
    }
    __syncthreads();

    const int mol = tid >> 4;               // phase-B mapping
    const int p0  = (tid & 15) * 2;

    for (int t = 0; t < Aat; ++t) {
        // ---- phase A: MFMA gh ----
        short8v hb[10];
        #pragma unroll
        for (int kf = 0; kf < 10; ++kf)
            hb[kf] = *(const short8v*)&Hsb[l15][kf * 32 + quad * 8];
        for (int tile = w; tile < 57; tile += 4) {
            const bf16* ap = WP + (long)(tile * 16 + l15) * 320 + quad * 8;
            float4v acc = (float4v){0.f, 0.f, 0.f, 0.f};
            #pragma unroll
            for (int kf = 0; kf < 10; ++kf)
                acc = __builtin_amdgcn_mfma_f32_16x16x32_bf16(
                    *(const short8v*)(ap + kf * 32), hb[kf], acc, 0, 0, 0);
            *(float4*)&GHs[l15][tile * 16 + quad * 4] = *(float4*)&acc;
        }
        __syncthreads();
        // ---- phase B: gates + state update (pairs of h) ----
        const int a = dir ? (Aat - 1 - t) : t;
        const long row = (long)(m0 + mol) * Aat + a;
        const bf16* girow = gi + row * 900;
        bf16* orow = out + row * 600 + (long)dir * 300;
        for (int hp = p0; hp < Hd; hp += 32) {
            const uint gr = *(const uint*)(girow + hp);
            const uint gz = *(const uint*)(girow + 300 + hp);
            const uint gn = *(const uint*)(girow + 600 + hp);
            const float2 br = *(const float2*)(bhh + hp);
            const float2 bz = *(const float2*)(bhh + 300 + hp);
            const float2 bn = *(const float2*)(bhh + 600 + hp);
            const float2 hr = *(const float2*)&GHs[mol][hp];
            const float2 hz = *(const float2*)&GHs[mol][300 + hp];
            const float2 hn = *(const float2*)&GHs[mol][600 + hp];
            const float2 hold = *(const float2*)&Hsf[mol][hp];
            float hnew[2];
            #pragma unroll
            for (int j = 0; j < 2; ++j) {
                const float ir  = j ? bhi(gr) : blo(gr);
                const float iz  = j ? bhi(gz) : blo(gz);
                const float inn = j ? bhi(gn) : blo(gn);
                const float ghr = (j ? hr.y + br.y : hr.x + br.x);
                const float ghz = (j ? hz.y + bz.y : hz.x + bz.x);
                const float ghn = (j ? hn.y + bn.y : hn.x + bn.x);
                const float rr = 1.f / (1.f + __expf(-(ir + ghr)));
                const float zz = 1.f / (1.f + __expf(-(iz + ghz)));
                float nin = inn + rr * ghn;
                nin = fminf(fmaxf(nin, -15.f), 15.f);
                const float e2 = __expf(-2.f * nin);
                const float nn = (1.f - e2) / (1.f + e2);
                hnew[j] = (1.f - zz) * nn + zz * (j ? hold.y : hold.x);
            }
            *(float2*)&Hsf[mol][hp] = make_float2(hnew[0], hnew[1]);
            *(uint*)&Hsb[mol][hp]   = f2bu(hnew[0]) | (f2bu(hnew[1]) << 16);
            *(uint*)(orow + hp)     = f2bu(hnew[0]) | (f2bu(hnew[1]) << 16);
        }
        __syncthreads();
    }
}

// =====================================================================
extern "C" void kernel_launch(void* const* d_in, const int* in_sizes, int n_in,
                              void* d_out, int out_size, void* d_ws, size_t ws_size,
                              hipStream_t stream)
{
    (void)in_sizes; (void)n_in; (void)out_size; (void)ws_size;

    const float* f_atoms  = (const float*)d_in[0];
    const float* f_bonds  = (const float*)d_in[1];
    const int*   a2b      = (const int*)d_in[2];
    const int*   b2a      = (const int*)d_in[3];
    const int*   b2revb   = (const int*)d_in[4];
    const float* W_i_atom = (const float*)d_in[7];
    const float* W_i_bond = (const float*)d_in[8];
    const float* W_h      = (const float*)d_in[9];
    const float* lr_W     = (const float*)d_in[10];
    const float* W_o_W    = (const float*)d_in[11];
    const float* W_o_b    = (const float*)d_in[12];
    const float* gWih_f   = (const float*)d_in[13];
    const float* gWhh_f   = (const float*)d_in[14];
    const float* gbih_f   = (const float*)d_in[15];
    const float* gbhh_f   = (const float*)d_in[16];
    const float* gWih_b   = (const float*)d_in[17];
    const float* gWhh_b   = (const float*)d_in[18];
    const float* gbih_b   = (const float*)d_in[19];
    const float* gbhh_b   = (const float*)d_in[20];

    // ---- workspace: same 4-region footprint as proven R6 (~235.9 MB) ----
    const size_t F32A_B = (size_t)NP1 * Hd * 4;      // 39.32 MB
    const size_t BND_B  = (size_t)BP1 * Hd * 2;      // 78.64 MB
    const size_t H0_B   = (size_t)Mmol * Hd * 4;     // 0.61 MB
    const size_t WPM_B  = (size_t)912 * 320 * 2;     // 583,680 B

    size_t off = 0;
    auto alloc = [&](size_t b) { size_t r = off; off += (b + 255) & ~(size_t)255; return r; };
    const size_t r1_o = alloc(F32A_B);       // IA [1-7] -> {H0,WPm,NRb} [8-12] -> AH [13-14]
    const size_t r2_o = alloc(F32A_B);       // MA [3-7] -> GRU [12-13]
    const size_t r3_o = alloc(BND_B);        // IB/MB1 [2-7] -> NODE [8-9] -> GIF [10-12]
    const size_t r4_o = alloc(BND_B + 4096); // FB16 [1b-2] -> MB0 [4-6] -> CC [7-8] -> GIB [11-12]

    char* ws = (char*)d_ws;
    float* IA   = (float*)(ws + r1_o);
    float* H0p  = (float*)(ws + r1_o);
    bf16*  WPmf = (bf16*)(ws + r1_o + ((H0_B + 255) & ~(size_t)255));
    bf16*  WPmb = (bf16*)((char*)WPmf + ((WPM_B + 255) & ~(size_t)255));
    bf16*  NRb  = (bf16*)(ws + r1_o + (2u << 20));   // +2 MB, past H0/WPm
    float* AH   = (float*)(ws + r1_o);
    float* MAb  = (float*)(ws + r2_o);
    bf16*  GRU  = (bf16*)(ws + r2_o);
    bf16*  IB   = (bf16*)(ws + r3_o);
    bf16*  MB1  = IB;
    float* NODE = (float*)(ws + r3_o);
    bf16*  GIF  = (bf16*)(ws + r3_o);
    bf16*  FB16 = (bf16*)(ws + r4_o);
    bf16*  MB0  = (bf16*)(ws + r4_o);
    bf16*  CC   = (bf16*)(ws + r4_o);
    bf16*  GIB  = (bf16*)(ws + r4_o);
    float* OUT  = (float*)d_out;
    bf16*  WSC  = (bf16*)d_out;        // 614,400 B time-shared packed-weight scratch

    const dim3 blk(256);
    auto grdF = [](int n, int h) { return dim3((n + BMr - 1) / BMr, (h + BNc - 1) / BNc); };
    auto grdM = [](int n, int h) { return dim3((h + 63) / 64, (n + 127) / 128); };
    auto pk = [&](const float* W, bf16* Wp, int h, int K, long hp, int Kp) {
        const long tot = hp * Kp;
        pack_w<<<dim3((tot + 255) / 256), blk, 0, stream>>>(W, Wp, h, K, tot, Kp);
    };

    // 1. IA = relu(f_atoms @ W_i_atom^T) -> f32 (VALU, full precision)
    gemm_ia<<<grdF(NP1, Hd), blk, 0, stream>>>(f_atoms, W_i_atom, IA, NP1, AF, Hd);
    // 1b. pack f_bonds -> bf16 [BP1][160]; W_i_bond -> [320][160] @d_out
    pk(f_bonds, FB16, BP1, BFd, BP1, 160);
    pk(W_i_bond, WSC, Hd, BFd, 320, 160);
    // 2. IB = relu(FB16 @ WIB^T)   [MFMA]
    mgemm<0, true, false, false, true, false, 0><<<grdM(BP1, Hd), blk, 0, stream>>>(
        FB16, nullptr, nullptr, nullptr, nullptr, WSC, nullptr, nullptr,
        IB, nullptr, BP1, 160, 160, Hd);
    // 3. MA = IA + sum*max(IB gathered)
    agg_kernel<true><<<NP1, 320, 0, stream>>>(IB, a2b, IA, MAb, 0);
    pk(W_h, WSC, Hd, Hd, 320, 320);
    // 4. MB0 = relu(IB + (MA[b2a]-IB[b2revb]) @ Wh0^T)   [MFMA fused gather]
    mgemm<3, true, false, true, true, false, 12><<<grdM(BP1, Hd), blk, 0, stream>>>(
        nullptr, MAb, IB, b2a, b2revb, WSC, nullptr, IB,
        MB0, nullptr, BP1, Hd, 320, Hd);
    // 5. MA += sum*max(MB0 gathered)
    agg_kernel<true><<<NP1, 320, 0, stream>>>(MB0, a2b, MAb, MAb, 0);
    pk(W_h + 300 * 300, WSC, Hd, Hd, 320, 320);
    // 6. MB1(=IB) = relu(IB + (MA[b2a]-MB0[b2revb]) @ Wh1^T)
    mgemm<3, true, false, true, true, false, 12><<<grdM(BP1, Hd), blk, 0, stream>>>(
        nullptr, MAb, MB0, b2a, b2revb, WSC, nullptr, IB,
        MB1, nullptr, BP1, Hd, 320, Hd);
    // 7. CC = concat3 bf16 (agg(MB1) | MA | IA), segment-padded to 960
    cc_build<<<Nat, 320, 0, stream>>>(MB1, a2b, MAb, IA, CC);
    pack_lrw<<<(320 * 960 + 255) / 256, blk, 0, stream>>>(lr_W, WSC);
    // 8. node = CC @ lrWp^T -> NODE f32 (pre-relu) + NRb bf16 (relu)  [MFMA]
    mgemm<0, false, false, false, false, true, 0><<<grdM(Nat, Hd), blk, 0, stream>>>(
        CC, nullptr, nullptr, nullptr, nullptr, WSC, nullptr, nullptr,
        NODE, NRb, Nat, 960, 960, Hd);
    // 9. h0 + GRU Whh packs (r1: IA dead)
    h0_kernel<<<Mmol, 320, 0, stream>>>(NODE, H0p);
    pk(gWhh_f, WPmf, 900, Hd, 912, 320);
    pk(gWhh_b, WPmb, 900, Hd, 912, 320);
    // 10. GIF = NRb @ gWih_f^T + gbih_f   [MFMA]
    pk(gWih_f, WSC, 900, Hd, 960, 320);
    mgemm<0, false, true, false, true, false, 12><<<grdM(Nat, 900), blk, 0, stream>>>(
        NRb, nullptr, nullptr, nullptr, nullptr, WSC, gbih_f, nullptr,
        GIF, nullptr, Nat, Hd, 320, 900);
    // 11. GIB likewise
    pk(gWih_b, WSC, 900, Hd, 960, 320);
    mgemm<0, false, true, false, true, false, 12><<<grdM(Nat, 900), blk, 0, stream>>>(
        NRb, nullptr, nullptr, nullptr, nullptr, WSC, gbih_b, nullptr,
        GIB, nullptr, Nat, Hd, 320, 900);
    // 12. MFMA bidirectional GRU
    gru3_kernel<<<(Mmol / GG) * 2, blk, 0, stream>>>(
        GIF, GIB, WPmf, WPmb, gbhh_f, gbhh_b, H0p, GRU);
    // 13. AH = relu(GRU @ W_o_W^T + W_o_b)   [MFMA]
    pk(W_o_W, WSC, Hd, 600, 320, 608);
    mgemm<0, true, true, false, false, false, 24><<<grdM(Nat, Hd), blk, 0, stream>>>(
        GRU, nullptr, nullptr, nullptr, nullptr, WSC, W_o_b, nullptr,
        AH, nullptr, Nat, 600, 608, Hd);
    // 14. mol_vecs = mean -> d_out
    mean_kernel<<<Mmol, 320, 0, stream>>>(AH, OUT);
}

// Round 8
// 2500.001 us; speedup vs baseline: 5.6671x; 1.1711x over previous
//
#include <hip/hip_runtime.h>
#include <hip/hip_bf16.h>

using bf16 = __hip_bfloat16;
using uint = unsigned int;
typedef __attribute__((ext_vector_type(8))) short short8v;   // 8 x bf16 MFMA operand
typedef __attribute__((ext_vector_type(4))) float float4v;   // MFMA accumulator

__device__ __forceinline__ float b2f(bf16 x){ return __bfloat162float(x); }
__device__ __forceinline__ bf16  f2b(float x){ return __float2bfloat16(x); }
__device__ __forceinline__ uint f2bu(float x){            // bf16 bits, RNE
    uint u = __float_as_uint(x);
    return (u + 0x7fffu + ((u >> 16) & 1u)) >> 16;
}
__device__ __forceinline__ float blo(uint u){ return __uint_as_float(u << 16); }
__device__ __forceinline__ float bhi(uint u){ return __uint_as_float(u & 0xffff0000u); }

// ---------------- problem constants ----------------
constexpr int Mmol = 512, Aat = 64;
constexpr int Nat  = Mmol * Aat;      // 32768
constexpr int NP1  = Nat + 1;
constexpr int Bnd  = Nat * 4;         // 131072
constexpr int BP1  = Bnd + 1;
constexpr int Hd   = 300;
constexpr int AF   = 133, BFd = 147;
constexpr int NB   = 6;

// =====================================================================
// MFMA GEMM (proven R6/R7): C[n,h] = act( A[n,K] @ Wp[h,Kp]^T (+bias)(+res) )
// =====================================================================
template<int AM, bool RELU, bool BIAS, bool RES, bool OUTBF16, bool DUAL, int TAILK>
__global__ __launch_bounds__(256) void mgemm(
    const bf16* __restrict__ Abh, const float* __restrict__ MAf, const bf16* __restrict__ MBh,
    const int* __restrict__ g1, const int* __restrict__ g2,
    const bf16* __restrict__ Wp, const float* __restrict__ bias, const bf16* __restrict__ res,
    void* __restrict__ Cp, bf16* __restrict__ Cp2, int n, int K, int Kp, int h)
{
    const int tid  = threadIdx.x;
    const int lane = tid & 63, w = tid >> 6;
    const int l15  = lane & 15, quad = lane >> 4;
    const long rowBase = (long)blockIdx.y * 128;
    const long colBase = (long)blockIdx.x * 64;

    long arow[2], ga[2], gb[2];
    #pragma unroll
    for (int mt = 0; mt < 2; ++mt) {
        long r = rowBase + w * 32 + mt * 16 + l15;
        if (r >= n) r = n - 1;               // clamped rows: garbage acc, never stored
        arow[mt] = r;
        if constexpr (AM == 3) { ga[mt] = g1[r]; gb[mt] = g2[r]; }
        else { ga[mt] = 0; gb[mt] = 0; }
    }

    const bf16* wp0 = Wp + (colBase + l15) * (long)Kp + quad * 8;

    float4v acc[2][4];
    #pragma unroll
    for (int mt = 0; mt < 2; ++mt)
        #pragma unroll
        for (int nt = 0; nt < 4; ++nt)
            acc[mt][nt] = (float4v){0.f, 0.f, 0.f, 0.f};

    const int ktiles = (K + 31) / 32;
    for (int kt = 0; kt < ktiles; ++kt) {
        const int kb = kt * 32;
        const int koff = kb + quad * 8;
        short8v bfr[4];
        #pragma unroll
        for (int nt = 0; nt < 4; ++nt)
            bfr[nt] = *(const short8v*)(wp0 + (long)nt * 16 * Kp + kb);
        short8v af[2];
        if constexpr (AM == 0) {
            #pragma unroll
            for (int mt = 0; mt < 2; ++mt) {
                const bf16* p = Abh + arow[mt] * (long)K + koff;
                union { uint2 u2[2]; short8v s; } t;
                t.u2[0] = *(const uint2*)p;
                t.u2[1] = *(const uint2*)(p + 4);
                af[mt] = t.s;
            }
        } else {   // AM == 3 fused gather-sub
            #pragma unroll
            for (int mt = 0; mt < 2; ++mt) {
                const float* pa = MAf + ga[mt] * 300 + koff;
                const bf16*  pb = MBh + gb[mt] * 300 + koff;
                const float4 m0 = *(const float4*)pa;
                const float4 m1 = *(const float4*)(pa + 4);
                const uint2  u0 = *(const uint2*)pb;
                const uint2  u1 = *(const uint2*)(pb + 4);
                float v[8];
                v[0] = m0.x - blo(u0.x); v[1] = m0.y - bhi(u0.x);
                v[2] = m0.z - blo(u0.y); v[3] = m0.w - bhi(u0.y);
                v[4] = m1.x - blo(u1.x); v[5] = m1.y - bhi(u1.x);
                v[6] = m1.z - blo(u1.y); v[7] = m1.w - bhi(u1.y);
                short8v s;
                #pragma unroll
                for (int j = 0; j < 8; ++j) s[j] = (short)f2bu(v[j]);
                af[mt] = s;
            }
        }
        if constexpr (TAILK != 0) {
            if (kb + 32 > K) {               // uniform branch, last tile only
                #pragma unroll
                for (int j = 0; j < 8; ++j)
                    if (koff + j >= K) { af[0][j] = 0; af[1][j] = 0; }
            }
        }
        #pragma unroll
        for (int mt = 0; mt < 2; ++mt)
            #pragma unroll
            for (int nt = 0; nt < 4; ++nt)
                acc[mt][nt] = __builtin_amdgcn_mfma_f32_16x16x32_bf16(
                    af[mt], bfr[nt], acc[mt][nt], 0, 0, 0);
    }

    float biasv[4];
    #pragma unroll
    for (int nt = 0; nt < 4; ++nt) {
        const long c = colBase + nt * 16 + l15;
        biasv[nt] = (BIAS && c < h) ? bias[c] : 0.f;
    }
    #pragma unroll
    for (int mt = 0; mt < 2; ++mt) {
        #pragma unroll
        for (int reg = 0; reg < 4; ++reg) {
            const long r = rowBase + w * 32 + mt * 16 + quad * 4 + reg;
            if (r < n) {
                #pragma unroll
                for (int nt = 0; nt < 4; ++nt) {
                    const long c = colBase + nt * 16 + l15;
                    if (c < h) {
                        float v = acc[mt][nt][reg];
                        if constexpr (RES)  v += b2f(res[r * (long)h + c]);
                        if constexpr (BIAS) v += biasv[nt];
                        if constexpr (RELU) v = fmaxf(v, 0.f);
                        if constexpr (DUAL) {
                            ((float*)Cp)[r * (long)h + c] = v;
                            Cp2[r * (long)h + c] = f2b(fmaxf(v, 0.f));
                        } else if constexpr (OUTBF16) {
                            ((bf16*)Cp)[r * (long)h + c] = f2b(v);
                        } else {
                            ((float*)Cp)[r * (long)h + c] = v;
                        }
                    }
                }
            }
        }
    }
}

// =====================================================================
__global__ __launch_bounds__(256) void pack_w(const float* __restrict__ W, bf16* __restrict__ Wp,
                                              int h, int K, long total, int Kp)
{
    const long idx = (long)blockIdx.x * 256 + threadIdx.x;
    if (idx >= total) return;
    const long r = idx / Kp;
    const int kk = (int)(idx - r * Kp);
    Wp[idx] = (r < h && kk < K) ? f2b(W[r * (long)K + kk]) : f2b(0.f);
}

// lr_W [300][900] -> Wp [320][960] bf16, segment-padded (3 x 300->320)
__global__ __launch_bounds__(256) void pack_lrw(const float* __restrict__ W, bf16* __restrict__ Wp)
{
    const int idx = blockIdx.x * 256 + threadIdx.x;
    if (idx >= 320 * 960) return;
    const int r = idx / 960, c = idx - r * 960;
    const int seg = c / 320, kk = c - seg * 320;
    Wp[idx] = (r < 300 && kk < 300) ? f2b(W[r * 900 + seg * 300 + kk]) : f2b(0.f);
}

// =====================================================================
// f32 VALU GEMM (IA only, k=133; keeps f_atoms at full precision)
// =====================================================================
constexpr int BMr = 256, BNc = 64;

__global__ __launch_bounds__(256) void gemm_ia(
    const float* __restrict__ A, const float* __restrict__ W,
    float* __restrict__ Cp, int n, int k, int h)
{
    __shared__ float As[16][BMr];
    __shared__ float Ws[16][BNc];

    const int tid = threadIdx.x;
    const int tx = tid & 7, ty = tid >> 3;
    const long rowBase = (long)blockIdx.x * BMr;
    const long colBase = (long)blockIdx.y * BNc;

    const long grow = rowBase + tid;
    const bool rv = grow < n;
    const int wcol = tid & 63, kq = tid >> 6;
    const long gcol = colBase + wcol;
    const bool cvv = gcol < h;

    float acc[8][8] = {};

    const int ktiles = (k + 15) / 16;
    for (int kt = 0; kt < ktiles; ++kt) {
        const int kb = kt * 16;
        __syncthreads();
        const float* ap = A + grow * (long)k + kb;
        #pragma unroll
        for (int c = 0; c < 16; ++c)
            As[c][tid] = (rv && kb + c < k) ? ap[c] : 0.f;
        #pragma unroll
        for (int c = 0; c < 4; ++c) {
            const int kk = kb + kq * 4 + c;
            Ws[kq * 4 + c][wcol] = (cvv && kk < k) ? W[gcol * (long)k + kk] : 0.f;
        }
        __syncthreads();
        #pragma unroll
        for (int kk = 0; kk < 16; ++kk) {
            const float4 a0 = *(const float4*)&As[kk][ty * 8];
            const float4 a1 = *(const float4*)&As[kk][ty * 8 + 4];
            const float4 b0 = *(const float4*)&Ws[kk][tx * 8];
            const float4 b1 = *(const float4*)&Ws[kk][tx * 8 + 4];
            const float aa[8] = {a0.x,a0.y,a0.z,a0.w,a1.x,a1.y,a1.z,a1.w};
            const float bb[8] = {b0.x,b0.y,b0.z,b0.w,b1.x,b1.y,b1.z,b1.w};
            #pragma unroll
            for (int i = 0; i < 8; ++i)
                #pragma unroll
                for (int j = 0; j < 8; ++j)
                    acc[i][j] = fmaf(aa[i], bb[j], acc[i][j]);
        }
    }
    #pragma unroll
    for (int i = 0; i < 8; ++i) {
        const long r = rowBase + ty * 8 + i;
        if (r < n) {
            #pragma unroll
            for (int j = 0; j < 8; ++j) {
                const long c = colBase + tx * 8 + j;
                if (c < h) Cp[r * (long)h + c] = fmaxf(acc[i][j], 0.f);
            }
        }
    }
}

// =====================================================================
template<bool ADD>
__global__ __launch_bounds__(320) void agg_kernel(
    const bf16* __restrict__ MB, const int* __restrict__ a2b,
    const float* __restrict__ src, float* __restrict__ out, int rowoff)
{
    const int hh = threadIdx.x;
    if (hh >= Hd) return;
    const long atom = (long)blockIdx.x + rowoff;
    const int* nb = a2b + atom * NB;
    float s = 0.f, mx = -1e30f;
    #pragma unroll
    for (int j = 0; j < NB; ++j) {
        const float v = b2f(MB[(long)nb[j] * Hd + hh]);
        s += v; mx = fmaxf(mx, v);
    }
    const float agg = s * mx;
    const long o = (long)blockIdx.x * Hd + hh;
    if constexpr (ADD) out[o] = src[atom * Hd + hh] + agg;
    else               out[o] = agg;
}

// cc_build: CC[r][0:300)=sum*max(MB1 gather), [320:620)=MA, [640:940)=IA, pads 0
__global__ __launch_bounds__(320) void cc_build(
    const bf16* __restrict__ MB, const int* __restrict__ a2b,
    const float* __restrict__ MA, const float* __restrict__ IA,
    bf16* __restrict__ CC)
{
    const int hh = threadIdx.x;
    const long r = blockIdx.x;          // 0..Nat-1, atom = r+1
    bf16* cr = CC + r * 960;
    if (hh < Hd) {
        const long atom = r + 1;
        const int* nb = a2b + atom * NB;
        float s = 0.f, mx = -1e30f;
        #pragma unroll
        for (int j = 0; j < NB; ++j) {
            const float v = b2f(MB[(long)nb[j] * Hd + hh]);
            s += v; mx = fmaxf(mx, v);
        }
        cr[hh]       = f2b(s * mx);
        cr[320 + hh] = f2b(MA[atom * Hd + hh]);
        cr[640 + hh] = f2b(IA[atom * Hd + hh]);
    } else {
        const int p = hh - Hd;          // 0..19
        cr[300 + p] = f2b(0.f);
        cr[620 + p] = f2b(0.f);
        cr[940 + p] = f2b(0.f);
    }
}

__global__ __launch_bounds__(320) void h0_kernel(const float* __restrict__ node, float* __restrict__ h0)
{
    const int hh = threadIdx.x;
    if (hh >= Hd) return;
    const long m = blockIdx.x;
    float mx = -1e30f;
    for (int a = 0; a < Aat; ++a)
        mx = fmaxf(mx, node[(m * Aat + a) * (long)Hd + hh]);
    h0[m * Hd + hh] = mx;
}

__global__ __launch_bounds__(320) void mean_kernel(const float* __restrict__ AH, float* __restrict__ out)
{
    const int hh = threadIdx.x;
    if (hh >= Hd) return;
    const long m = blockIdx.x;
    float s = 0.f;
    for (int a = 0; a < Aat; ++a)
        s += AH[(m * Aat + a) * (long)Hd + hh];
    out[m * Hd + hh] = s * (1.f / 64.f);
}

// =====================================================================
// gru4: register-resident-Whh MFMA GRU.
// Grid 256 blocks x 1024 threads (16 waves/CU, full chip). One block =
// 4 (mol) x 1 dir. Each wave permanently holds 4 row-tiles of Whh in
// VGPRs (loaded ONCE; fixes gru3's per-step 583KB L2 re-fetch at 3%
// occupancy). Per step: B-frag = h (bf16 LDS mirror, mols on lanes,
// R6/R7-proven operand pattern), 40 reg-resident MFMAs -> gh in LDS;
// gates on 600 threads with gi prefetched before the barrier.
// WP is [1024][320] bf16 zero-padded so all tile loads are in-bounds.
// =====================================================================
constexpr int GM = 4;   // mols per block

__global__ __launch_bounds__(1024) void gru4_kernel(
    const bf16* __restrict__ gi_f, const bf16* __restrict__ gi_b,
    const bf16* __restrict__ WPf, const bf16* __restrict__ WPb,   // [1024][320]
    const float* __restrict__ bhh_f, const float* __restrict__ bhh_b,
    const float* __restrict__ h0, bf16* __restrict__ out)
{
    const int dir = blockIdx.x & 1;
    const int m0  = (blockIdx.x >> 1) * GM;
    const bf16*  WP  = dir ? WPb : WPf;
    const float* bhh = dir ? bhh_b : bhh_f;
    const bf16*  gi  = dir ? gi_b  : gi_f;

    __shared__ float Hsf[GM][304];      // f32 master h
    __shared__ short Hsb[GM][328];      // bf16 mirror (16B-aligned rows, pad=0)
    __shared__ float GHs[GM][1028];     // gh per mol (rows 0..1023; >=900 unused)

    const int tid  = threadIdx.x;
    const int lane = tid & 63, w = tid >> 6;
    const int l15  = lane & 15, quad = lane >> 4;

    // ---- init h (f32 + bf16 mirror, zero pads) ----
    for (int idx = tid; idx < GM * 328; idx += 1024) {
        const int g = idx / 328, hh = idx - g * 328;
        const float v = (hh < Hd) ? h0[(long)(m0 + g) * Hd + hh] : 0.f;
        if (hh < 304) Hsf[g][hh] = v;
        Hsb[g][hh] = (short)f2bu(v);
    }

    // ---- load Whh A-frags into registers ONCE (4 tiles/wave) ----
    short8v afr[4][10];
    #pragma unroll
    for (int i = 0; i < 4; ++i) {
        const int tile = w + i * 16;                    // 0..63 (rows < 1024)
        const bf16* ap = WP + (long)(tile * 16 + l15) * 320 + quad * 8;
        #pragma unroll
        for (int kf = 0; kf < 10; ++kf)
            afr[i][kf] = *(const short8v*)(ap + kf * 32);
    }

    // ---- phase-B per-thread constants ----
    const bool pOK = tid < 600;
    const int pmol = pOK ? tid / 150 : 0;
    const int hp   = pOK ? (tid - pmol * 150) * 2 : 0;
    const float2 br = pOK ? *(const float2*)(bhh + hp)       : make_float2(0.f, 0.f);
    const float2 bz = pOK ? *(const float2*)(bhh + 300 + hp) : make_float2(0.f, 0.f);
    const float2 bn = pOK ? *(const float2*)(bhh + 600 + hp) : make_float2(0.f, 0.f);
    const bf16* giBase = gi + (long)(m0 + pmol) * Aat * 900;
    bf16* outBase = out + ((long)(m0 + pmol) * Aat) * 600 + (long)dir * 300;

    __syncthreads();

    for (int t = 0; t < Aat; ++t) {
        const int a = dir ? (Aat - 1 - t) : t;
        // ---- gi prefetch (overlaps phase-A MFMA) ----
        uint gr = 0, gz = 0, gn = 0;
        if (pOK) {
            const bf16* girow = giBase + (long)a * 900;
            gr = *(const uint*)(girow + hp);
            gz = *(const uint*)(girow + 300 + hp);
            gn = *(const uint*)(girow + 600 + hp);
        }
        // ---- phase A: gh = Whh @ h (register A, LDS B) ----
        short8v hb[10];
        #pragma unroll
        for (int kf = 0; kf < 10; ++kf)
            hb[kf] = *(const short8v*)&Hsb[l15 & (GM - 1)][kf * 32 + quad * 8];
        #pragma unroll
        for (int i = 0; i < 4; ++i) {
            float4v acc = (float4v){0.f, 0.f, 0.f, 0.f};
            #pragma unroll
            for (int kf = 0; kf < 10; ++kf)
                acc = __builtin_amdgcn_mfma_f32_16x16x32_bf16(afr[i][kf], hb[kf], acc, 0, 0, 0);
            if (l15 < GM)
                *(float4*)&GHs[l15][(w + i * 16) * 16 + quad * 4] = *(float4*)&acc;
        }
        __syncthreads();
        // ---- phase B: gates + state update ----
        if (pOK) {
            const float2 hr = *(const float2*)&GHs[pmol][hp];
            const float2 hz = *(const float2*)&GHs[pmol][300 + hp];
            const float2 hn = *(const float2*)&GHs[pmol][600 + hp];
            const float2 hold = *(const float2*)&Hsf[pmol][hp];
            float hnew[2];
            #pragma unroll
            for (int j = 0; j < 2; ++j) {
                const float ir  = j ? bhi(gr) : blo(gr);
                const float iz  = j ? bhi(gz) : blo(gz);
                const float inn = j ? bhi(gn) : blo(gn);
                const float ghr = (j ? hr.y + br.y : hr.x + br.x);
                const float ghz = (j ? hz.y + bz.y : hz.x + bz.x);
                const float ghn = (j ? hn.y + bn.y : hn.x + bn.x);
                const float rr = 1.f / (1.f + __expf(-(ir + ghr)));
                const float zz = 1.f / (1.f + __expf(-(iz + ghz)));
                float nin = inn + rr * ghn;
                nin = fminf(fmaxf(nin, -15.f), 15.f);
                const float e2 = __expf(-2.f * nin);
                const float nnv = (1.f - e2) / (1.f + e2);
                hnew[j] = (1.f - zz) * nnv + zz * (j ? hold.y : hold.x);
            }
            const uint pk2 = f2bu(hnew[0]) | (f2bu(hnew[1]) << 16);
            *(float2*)&Hsf[pmol][hp] = make_float2(hnew[0], hnew[1]);
            *(uint*)&Hsb[pmol][hp]   = pk2;
            *(uint*)(outBase + (long)a * 600 + hp) = pk2;
        }
        __syncthreads();
    }
}

// =====================================================================
extern "C" void kernel_launch(void* const* d_in, const int* in_sizes, int n_in,
                              void* d_out, int out_size, void* d_ws, size_t ws_size,
                              hipStream_t stream)
{
    (void)in_sizes; (void)n_in; (void)out_size; (void)ws_size;

    const float* f_atoms  = (const float*)d_in[0];
    const float* f_bonds  = (const float*)d_in[1];
    const int*   a2b      = (const int*)d_in[2];
    const int*   b2a      = (const int*)d_in[3];
    const int*   b2revb   = (const int*)d_in[4];
    const float* W_i_atom = (const float*)d_in[7];
    const float* W_i_bond = (const float*)d_in[8];
    const float* W_h      = (const float*)d_in[9];
    const float* lr_W     = (const float*)d_in[10];
    const float* W_o_W    = (const float*)d_in[11];
    const float* W_o_b    = (const float*)d_in[12];
    const float* gWih_f   = (const float*)d_in[13];
    const float* gWhh_f   = (const float*)d_in[14];
    const float* gbih_f   = (const float*)d_in[15];
    const float* gbhh_f   = (const float*)d_in[16];
    const float* gWih_b   = (const float*)d_in[17];
    const float* gWhh_b   = (const float*)d_in[18];
    const float* gbih_b   = (const float*)d_in[19];
    const float* gbhh_b   = (const float*)d_in[20];

    // ---- workspace: same 4-region footprint as proven R6/R7 (~235.9 MB) ----
    const size_t F32A_B = (size_t)NP1 * Hd * 4;      // 39.32 MB
    const size_t BND_B  = (size_t)BP1 * Hd * 2;      // 78.64 MB
    const size_t H0_B   = (size_t)Mmol * Hd * 4;     // 614,400 B
    const size_t WPM_B  = (size_t)1024 * 320 * 2;    // 655,360 B (padded rows)

    size_t off = 0;
    auto alloc = [&](size_t b) { size_t r = off; off += (b + 255) & ~(size_t)255; return r; };
    const size_t r1_o = alloc(F32A_B);       // IA [1-7] -> {H0,WPm,NRb} [8-12] -> AH [13-14]
    const size_t r2_o = alloc(F32A_B);       // MA [3-7] -> GRU [12-13]
    const size_t r3_o = alloc(BND_B);        // IB/MB1 [2-7] -> NODE [8-9] -> GIF [10-12]
    const size_t r4_o = alloc(BND_B + 4096); // FB16 [1b-2] -> MB0 [4-6] -> CC [7-8] -> GIB [11-12]

    char* ws = (char*)d_ws;
    float* IA   = (float*)(ws + r1_o);
    float* H0p  = (float*)(ws + r1_o);
    bf16*  WPmf = (bf16*)(ws + r1_o + ((H0_B + 255) & ~(size_t)255));
    bf16*  WPmb = (bf16*)((char*)WPmf + ((WPM_B + 255) & ~(size_t)255));
    bf16*  NRb  = (bf16*)(ws + r1_o + (2u << 20));   // +2 MB (614K+656K+656K = 1.93 MB used)
    float* AH   = (float*)(ws + r1_o);
    float* MAb  = (float*)(ws + r2_o);
    bf16*  GRU  = (bf16*)(ws + r2_o);
    bf16*  IB   = (bf16*)(ws + r3_o);
    bf16*  MB1  = IB;
    float* NODE = (float*)(ws + r3_o);
    bf16*  GIF  = (bf16*)(ws + r3_o);
    bf16*  FB16 = (bf16*)(ws + r4_o);
    bf16*  MB0  = (bf16*)(ws + r4_o);
    bf16*  CC   = (bf16*)(ws + r4_o);
    bf16*  GIB  = (bf16*)(ws + r4_o);
    const size_t GI_B = (size_t)Nat * 900 * 2;       // 58.98 MB (r4 sub-layout)
    (void)GI_B;
    float* OUT  = (float*)d_out;
    bf16*  WSC  = (bf16*)d_out;        // 614,400 B time-shared packed-weight scratch

    const dim3 blk(256);
    auto grdF = [](int n, int h) { return dim3((n + BMr - 1) / BMr, (h + BNc - 1) / BNc); };
    auto grdM = [](int n, int h) { return dim3((h + 63) / 64, (n + 127) / 128); };
    auto pk = [&](const float* W, bf16* Wp, int h, int K, long hp, int Kp) {
        const long tot = hp * Kp;
        pack_w<<<dim3((tot + 255) / 256), blk, 0, stream>>>(W, Wp, h, K, tot, Kp);
    };

    // 1. IA = relu(f_atoms @ W_i_atom^T) -> f32 (VALU, full precision)
    gemm_ia<<<grdF(NP1, Hd), blk, 0, stream>>>(f_atoms, W_i_atom, IA, NP1, AF, Hd);
    // 1b. pack f_bonds -> bf16 [BP1][160]; W_i_bond -> [320][160] @d_out
    pk(f_bonds, FB16, BP1, BFd, BP1, 160);
    pk(W_i_bond, WSC, Hd, BFd, 320, 160);
    // 2. IB = relu(FB16 @ WIB^T)   [MFMA]
    mgemm<0, true, false, false, true, false, 0><<<grdM(BP1, Hd), blk, 0, stream>>>(
        FB16, nullptr, nullptr, nullptr, nullptr, WSC, nullptr, nullptr,
        IB, nullptr, BP1, 160, 160, Hd);
    // 3. MA = IA + sum*max(IB gathered)
    agg_kernel<true><<<NP1, 320, 0, stream>>>(IB, a2b, IA, MAb, 0);
    pk(W_h, WSC, Hd, Hd, 320, 320);
    // 4. MB0 = relu(IB + (MA[b2a]-IB[b2revb]) @ Wh0^T)   [MFMA fused gather]
    mgemm<3, true, false, true, true, false, 12><<<grdM(BP1, Hd), blk, 0, stream>>>(
        nullptr, MAb, IB, b2a, b2revb, WSC, nullptr, IB,
        MB0, nullptr, BP1, Hd, 320, Hd);
    // 5. MA += sum*max(MB0 gathered)
    agg_kernel<true><<<NP1, 320, 0, stream>>>(MB0, a2b, MAb, MAb, 0);
    pk(W_h + 300 * 300, WSC, Hd, Hd, 320, 320);
    // 6. MB1(=IB) = relu(IB + (MA[b2a]-MB0[b2revb]) @ Wh1^T)
    mgemm<3, true, false, true, true, false, 12><<<grdM(BP1, Hd), blk, 0, stream>>>(
        nullptr, MAb, MB0, b2a, b2revb, WSC, nullptr, IB,
        MB1, nullptr, BP1, Hd, 320, Hd);
    // 7. CC = concat3 bf16 (agg(MB1) | MA | IA), segment-padded to 960
    cc_build<<<Nat, 320, 0, stream>>>(MB1, a2b, MAb, IA, CC);
    pack_lrw<<<(320 * 960 + 255) / 256, blk, 0, stream>>>(lr_W, WSC);
    // 8. node = CC @ lrWp^T -> NODE f32 (pre-relu) + NRb bf16 (relu)  [MFMA]
    mgemm<0, false, false, false, false, true, 0><<<grdM(Nat, Hd), blk, 0, stream>>>(
        CC, nullptr, nullptr, nullptr, nullptr, WSC, nullptr, nullptr,
        NODE, NRb, Nat, 960, 960, Hd);
    // 9. h0 + GRU Whh packs (r1: IA dead). WP padded to 1024 rows (zeros).
    h0_kernel<<<Mmol, 320, 0, stream>>>(NODE, H0p);
    pk(gWhh_f, WPmf, 900, Hd, 1024, 320);
    pk(gWhh_b, WPmb, 900, Hd, 1024, 320);
    // 10. GIF = NRb @ gWih_f^T + gbih_f   [MFMA]
    pk(gWih_f, WSC, 900, Hd, 960, 320);
    mgemm<0, false, true, false, true, false, 12><<<grdM(Nat, 900), blk, 0, stream>>>(
        NRb, nullptr, nullptr, nullptr, nullptr, WSC, gbih_f, nullptr,
        GIF, nullptr, Nat, Hd, 320, 900);
    // 11. GIB likewise
    pk(gWih_b, WSC, 900, Hd, 960, 320);
    mgemm<0, false, true, false, true, false, 12><<<grdM(Nat, 900), blk, 0, stream>>>(
        NRb, nullptr, nullptr, nullptr, nullptr, WSC, gbih_b, nullptr,
        GIB, nullptr, Nat, Hd, 320, 900);
    // 12. register-resident MFMA bidirectional GRU
    gru4_kernel<<<(Mmol / GM) * 2, dim3(1024), 0, stream>>>(
        GIF, GIB, WPmf, WPmb, gbhh_f, gbhh_b, H0p, GRU);
    // 13. AH = relu(GRU @ W_o_W^T + W_o_b)   [MFMA]
    pk(W_o_W, WSC, Hd, 600, 320, 608);
    mgemm<0, true, true, false, false, false, 24><<<grdM(Nat, Hd), blk, 0, stream>>>(
        GRU, nullptr, nullptr, nullptr, nullptr, WSC, W_o_b, nullptr,
        AH, nullptr, Nat, 600, 608, Hd);
    // 14. mol_vecs = mean -> d_out
    mean_kernel<<<Mmol, 320, 0, stream>>>(AH, OUT);
}

// Round 9
// 2493.283 us; speedup vs baseline: 5.6824x; 1.0027x over previous
//
#include <hip/hip_runtime.h>
#include <hip/hip_bf16.h>

using bf16 = __hip_bfloat16;
using uint = unsigned int;
typedef __attribute__((ext_vector_type(8))) short short8v;   // 8 x bf16 MFMA operand
typedef __attribute__((ext_vector_type(4))) float float4v;   // MFMA accumulator

__device__ __forceinline__ float b2f(bf16 x){ return __bfloat162float(x); }
__device__ __forceinline__ bf16  f2b(float x){ return __float2bfloat16(x); }
__device__ __forceinline__ uint f2bu(float x){            // bf16 bits, RNE
    uint u = __float_as_uint(x);
    return (u + 0x7fffu + ((u >> 16) & 1u)) >> 16;
}
__device__ __forceinline__ float blo(uint u){ return __uint_as_float(u << 16); }
__device__ __forceinline__ float bhi(uint u){ return __uint_as_float(u & 0xffff0000u); }

// ---------------- problem constants ----------------
constexpr int Mmol = 512, Aat = 64;
constexpr int Nat  = Mmol * Aat;      // 32768
constexpr int NP1  = Nat + 1;
constexpr int Bnd  = Nat * 4;         // 131072
constexpr int BP1  = Bnd + 1;
constexpr int Hd   = 300;
constexpr int AF   = 133, BFd = 147;
constexpr int NB   = 6;

// =====================================================================
// MFMA GEMM (proven R6/R7): C[n,h] = act( A[n,K] @ Wp[h,Kp]^T (+bias)(+res) )
// =====================================================================
template<int AM, bool RELU, bool BIAS, bool RES, bool OUTBF16, bool DUAL, int TAILK>
__global__ __launch_bounds__(256) void mgemm(
    const bf16* __restrict__ Abh, const float* __restrict__ MAf, const bf16* __restrict__ MBh,
    const int* __restrict__ g1, const int* __restrict__ g2,
    const bf16* __restrict__ Wp, const float* __restrict__ bias, const bf16* __restrict__ res,
    void* __restrict__ Cp, bf16* __restrict__ Cp2, int n, int K, int Kp, int h)
{
    const int tid  = threadIdx.x;
    const int lane = tid & 63, w = tid >> 6;
    const int l15  = lane & 15, quad = lane >> 4;
    const long rowBase = (long)blockIdx.y * 128;
    const long colBase = (long)blockIdx.x * 64;

    long arow[2], ga[2], gb[2];
    #pragma unroll
    for (int mt = 0; mt < 2; ++mt) {
        long r = rowBase + w * 32 + mt * 16 + l15;
        if (r >= n) r = n - 1;               // clamped rows: garbage acc, never stored
        arow[mt] = r;
        if constexpr (AM == 3) { ga[mt] = g1[r]; gb[mt] = g2[r]; }
        else { ga[mt] = 0; gb[mt] = 0; }
    }

    const bf16* wp0 = Wp + (colBase + l15) * (long)Kp + quad * 8;

    float4v acc[2][4];
    #pragma unroll
    for (int mt = 0; mt < 2; ++mt)
        #pragma unroll
        for (int nt = 0; nt < 4; ++nt)
            acc[mt][nt] = (float4v){0.f, 0.f, 0.f, 0.f};

    const int ktiles = (K + 31) / 32;
    for (int kt = 0; kt < ktiles; ++kt) {
        const int kb = kt * 32;
        const int koff = kb + quad * 8;
        short8v bfr[4];
        #pragma unroll
        for (int nt = 0; nt < 4; ++nt)
            bfr[nt] = *(const short8v*)(wp0 + (long)nt * 16 * Kp + kb);
        short8v af[2];
        if constexpr (AM == 0) {
            #pragma unroll
            for (int mt = 0; mt < 2; ++mt) {
                const bf16* p = Abh + arow[mt] * (long)K + koff;
                union { uint2 u2[2]; short8v s; } t;
                t.u2[0] = *(const uint2*)p;
                t.u2[1] = *(const uint2*)(p + 4);
                af[mt] = t.s;
            }
        } else {   // AM == 3 fused gather-sub
            #pragma unroll
            for (int mt = 0; mt < 2; ++mt) {
                const float* pa = MAf + ga[mt] * 300 + koff;
                const bf16*  pb = MBh + gb[mt] * 300 + koff;
                const float4 m0 = *(const float4*)pa;
                const float4 m1 = *(const float4*)(pa + 4);
                const uint2  u0 = *(const uint2*)pb;
                const uint2  u1 = *(const uint2*)(pb + 4);
                float v[8];
                v[0] = m0.x - blo(u0.x); v[1] = m0.y - bhi(u0.x);
                v[2] = m0.z - blo(u0.y); v[3] = m0.w - bhi(u0.y);
                v[4] = m1.x - blo(u1.x); v[5] = m1.y - bhi(u1.x);
                v[6] = m1.z - blo(u1.y); v[7] = m1.w - bhi(u1.y);
                short8v s;
                #pragma unroll
                for (int j = 0; j < 8; ++j) s[j] = (short)f2bu(v[j]);
                af[mt] = s;
            }
        }
        if constexpr (TAILK != 0) {
            if (kb + 32 > K) {               // uniform branch, last tile only
                #pragma unroll
                for (int j = 0; j < 8; ++j)
                    if (koff + j >= K) { af[0][j] = 0; af[1][j] = 0; }
            }
        }
        #pragma unroll
        for (int mt = 0; mt < 2; ++mt)
            #pragma unroll
            for (int nt = 0; nt < 4; ++nt)
                acc[mt][nt] = __builtin_amdgcn_mfma_f32_16x16x32_bf16(
                    af[mt], bfr[nt], acc[mt][nt], 0, 0, 0);
    }

    float biasv[4];
    #pragma unroll
    for (int nt = 0; nt < 4; ++nt) {
        const long c = colBase + nt * 16 + l15;
        biasv[nt] = (BIAS && c < h) ? bias[c] : 0.f;
    }
    #pragma unroll
    for (int mt = 0; mt < 2; ++mt) {
        #pragma unroll
        for (int reg = 0; reg < 4; ++reg) {
            const long r = rowBase + w * 32 + mt * 16 + quad * 4 + reg;
            if (r < n) {
                #pragma unroll
                for (int nt = 0; nt < 4; ++nt) {
                    const long c = colBase + nt * 16 + l15;
                    if (c < h) {
                        float v = acc[mt][nt][reg];
                        if constexpr (RES)  v += b2f(res[r * (long)h + c]);
                        if constexpr (BIAS) v += biasv[nt];
                        if constexpr (RELU) v = fmaxf(v, 0.f);
                        if constexpr (DUAL) {
                            ((float*)Cp)[r * (long)h + c] = v;
                            Cp2[r * (long)h + c] = f2b(fmaxf(v, 0.f));
                        } else if constexpr (OUTBF16) {
                            ((bf16*)Cp)[r * (long)h + c] = f2b(v);
                        } else {
                            ((float*)Cp)[r * (long)h + c] = v;
                        }
                    }
                }
            }
        }
    }
}

// =====================================================================
__global__ __launch_bounds__(256) void pack_w(const float* __restrict__ W, bf16* __restrict__ Wp,
                                              int h, int K, long total, int Kp)
{
    const long idx = (long)blockIdx.x * 256 + threadIdx.x;
    if (idx >= total) return;
    const long r = idx / Kp;
    const int kk = (int)(idx - r * Kp);
    Wp[idx] = (r < h && kk < K) ? f2b(W[r * (long)K + kk]) : f2b(0.f);
}

// lr_W [300][900] -> Wp [320][960] bf16, segment-padded (3 x 300->320)
__global__ __launch_bounds__(256) void pack_lrw(const float* __restrict__ W, bf16* __restrict__ Wp)
{
    const int idx = blockIdx.x * 256 + threadIdx.x;
    if (idx >= 320 * 960) return;
    const int r = idx / 960, c = idx - r * 960;
    const int seg = c / 320, kk = c - seg * 320;
    Wp[idx] = (r < 300 && kk < 300) ? f2b(W[r * 900 + seg * 300 + kk]) : f2b(0.f);
}

// =====================================================================
// f32 VALU GEMM (IA only, k=133; keeps f_atoms at full precision)
// =====================================================================
constexpr int BMr = 256, BNc = 64;

__global__ __launch_bounds__(256) void gemm_ia(
    const float* __restrict__ A, const float* __restrict__ W,
    float* __restrict__ Cp, int n, int k, int h)
{
    __shared__ float As[16][BMr];
    __shared__ float Ws[16][BNc];

    const int tid = threadIdx.x;
    const int tx = tid & 7, ty = tid >> 3;
    const long rowBase = (long)blockIdx.x * BMr;
    const long colBase = (long)blockIdx.y * BNc;

    const long grow = rowBase + tid;
    const bool rv = grow < n;
    const int wcol = tid & 63, kq = tid >> 6;
    const long gcol = colBase + wcol;
    const bool cvv = gcol < h;

    float acc[8][8] = {};

    const int ktiles = (k + 15) / 16;
    for (int kt = 0; kt < ktiles; ++kt) {
        const int kb = kt * 16;
        __syncthreads();
        const float* ap = A + grow * (long)k + kb;
        #pragma unroll
        for (int c = 0; c < 16; ++c)
            As[c][tid] = (rv && kb + c < k) ? ap[c] : 0.f;
        #pragma unroll
        for (int c = 0; c < 4; ++c) {
            const int kk = kb + kq * 4 + c;
            Ws[kq * 4 + c][wcol] = (cvv && kk < k) ? W[gcol * (long)k + kk] : 0.f;
        }
        __syncthreads();
        #pragma unroll
        for (int kk = 0; kk < 16; ++kk) {
            const float4 a0 = *(const float4*)&As[kk][ty * 8];
            const float4 a1 = *(const float4*)&As[kk][ty * 8 + 4];
            const float4 b0 = *(const float4*)&Ws[kk][tx * 8];
            const float4 b1 = *(const float4*)&Ws[kk][tx * 8 + 4];
            const float aa[8] = {a0.x,a0.y,a0.z,a0.w,a1.x,a1.y,a1.z,a1.w};
            const float bb[8] = {b0.x,b0.y,b0.z,b0.w,b1.x,b1.y,b1.z,b1.w};
            #pragma unroll
            for (int i = 0; i < 8; ++i)
                #pragma unroll
                for (int j = 0; j < 8; ++j)
                    acc[i][j] = fmaf(aa[i], bb[j], acc[i][j]);
        }
    }
    #pragma unroll
    for (int i = 0; i < 8; ++i) {
        const long r = rowBase + ty * 8 + i;
        if (r < n) {
            #pragma unroll
            for (int j = 0; j < 8; ++j) {
                const long c = colBase + tx * 8 + j;
                if (c < h) Cp[r * (long)h + c] = fmaxf(acc[i][j], 0.f);
            }
        }
    }
}

// =====================================================================
template<bool ADD>
__global__ __launch_bounds__(320) void agg_kernel(
    const bf16* __restrict__ MB, const int* __restrict__ a2b,
    const float* __restrict__ src, float* __restrict__ out, int rowoff)
{
    const int hh = threadIdx.x;
    if (hh >= Hd) return;
    const long atom = (long)blockIdx.x + rowoff;
    const int* nb = a2b + atom * NB;
    float s = 0.f, mx = -1e30f;
    #pragma unroll
    for (int j = 0; j < NB; ++j) {
        const float v = b2f(MB[(long)nb[j] * Hd + hh]);
        s += v; mx = fmaxf(mx, v);
    }
    const float agg = s * mx;
    const long o = (long)blockIdx.x * Hd + hh;
    if constexpr (ADD) out[o] = src[atom * Hd + hh] + agg;
    else               out[o] = agg;
}

// cc_build: CC[r][0:300)=sum*max(MB1 gather), [320:620)=MA, [640:940)=IA, pads 0
__global__ __launch_bounds__(320) void cc_build(
    const bf16* __restrict__ MB, const int* __restrict__ a2b,
    const float* __restrict__ MA, const float* __restrict__ IA,
    bf16* __restrict__ CC)
{
    const int hh = threadIdx.x;
    const long r = blockIdx.x;          // 0..Nat-1, atom = r+1
    bf16* cr = CC + r * 960;
    if (hh < Hd) {
        const long atom = r + 1;
        const int* nb = a2b + atom * NB;
        float s = 0.f, mx = -1e30f;
        #pragma unroll
        for (int j = 0; j < NB; ++j) {
            const float v = b2f(MB[(long)nb[j] * Hd + hh]);
            s += v; mx = fmaxf(mx, v);
        }
        cr[hh]       = f2b(s * mx);
        cr[320 + hh] = f2b(MA[atom * Hd + hh]);
        cr[640 + hh] = f2b(IA[atom * Hd + hh]);
    } else {
        const int p = hh - Hd;          // 0..19
        cr[300 + p] = f2b(0.f);
        cr[620 + p] = f2b(0.f);
        cr[940 + p] = f2b(0.f);
    }
}

__global__ __launch_bounds__(320) void h0_kernel(const float* __restrict__ node, float* __restrict__ h0)
{
    const int hh = threadIdx.x;
    if (hh >= Hd) return;
    const long m = blockIdx.x;
    float mx = -1e30f;
    for (int a = 0; a < Aat; ++a)
        mx = fmaxf(mx, node[(m * Aat + a) * (long)Hd + hh]);
    h0[m * Hd + hh] = mx;
}

__global__ __launch_bounds__(320) void mean_kernel(const float* __restrict__ AH, float* __restrict__ out)
{
    const int hh = threadIdx.x;
    if (hh >= Hd) return;
    const long m = blockIdx.x;
    float s = 0.f;
    for (int a = 0; a < Aat; ++a)
        s += AH[(m * Aat + a) * (long)Hd + hh];
    out[m * Hd + hh] = s * (1.f / 64.f);
}

// =====================================================================
// gru5: L2-streamed-Whh MFMA GRU with full latency hiding.
// Grid 128 blocks x 1024 thr (16 waves). One block = 8 mols x 1 dir.
// Whh streamed from L2 every step (registers CANNOT hold it: 583KB >
// 512KB VGPR file/CU — gru4's "register-resident" spilled to scratch,
// 3.3GB HBM traffic). Per wave <=4 tiles; W-frags loaded in two 5-frag
// batches (peak live regs ~95 < the 128 cap at 1024 thr -> no spill).
// 16 waves/CU hide L2 latency; floor = per-CU L2 BW (~37MB/CU @ ~144GB/s).
// =====================================================================
constexpr int GG5 = 8;   // mols per block

__global__ __launch_bounds__(1024) void gru5_kernel(
    const bf16* __restrict__ gi_f, const bf16* __restrict__ gi_b,
    const bf16* __restrict__ WPf, const bf16* __restrict__ WPb,   // [1024][320]
    const float* __restrict__ bhh_f, const float* __restrict__ bhh_b,
    const float* __restrict__ h0, bf16* __restrict__ out)
{
    const int dir = blockIdx.x & 1;
    const int m0  = (blockIdx.x >> 1) * GG5;
    const bf16*  WP  = dir ? WPb : WPf;
    const float* bhh = dir ? bhh_b : bhh_f;
    const bf16*  gi  = dir ? gi_b  : gi_f;

    __shared__ float Hsf[GG5][304];     // f32 master h
    __shared__ short Hsb[GG5][328];     // bf16 mirror (16B-aligned rows, pad=0)
    __shared__ float GHs[GG5][916];     // gh per mol (916*4B = 16B-aligned rows)

    const int tid  = threadIdx.x;
    const int lane = tid & 63, w = tid >> 6;    // w: 0..15
    const int l15  = lane & 15, quad = lane >> 4;

    // ---- init h (f32 + bf16 mirror, zero pads) ----
    for (int idx = tid; idx < GG5 * 328; idx += 1024) {
        const int g = idx / 328, hh = idx - g * 328;
        const float v = (hh < Hd) ? h0[(long)(m0 + g) * Hd + hh] : 0.f;
        if (hh < 304) Hsf[g][hh] = v;
        Hsb[g][hh] = (short)f2bu(v);
    }

    // ---- phase-B constants: 1200 items over 1024 threads = 2 passes ----
    bool okA[2]; int pmolA[2], hpA[2];
    float2 brA[2], bzA[2], bnA[2];
    #pragma unroll
    for (int p = 0; p < 2; ++p) {
        const int idx = tid + p * 1024;
        okA[p] = idx < GG5 * 150;
        const int pm = okA[p] ? idx / 150 : 0;
        const int hp = okA[p] ? (idx - pm * 150) * 2 : 0;
        pmolA[p] = pm; hpA[p] = hp;
        brA[p] = okA[p] ? *(const float2*)(bhh + hp)       : make_float2(0.f, 0.f);
        bzA[p] = okA[p] ? *(const float2*)(bhh + 300 + hp) : make_float2(0.f, 0.f);
        bnA[p] = okA[p] ? *(const float2*)(bhh + 600 + hp) : make_float2(0.f, 0.f);
    }
    __syncthreads();

    for (int t = 0; t < Aat; ++t) {
        const int a = dir ? (Aat - 1 - t) : t;
        // ---- gi prefetch for both passes (overlaps phase-A) ----
        uint gr[2], gz[2], gn[2];
        #pragma unroll
        for (int p = 0; p < 2; ++p) {
            gr[p] = gz[p] = gn[p] = 0;
            if (okA[p]) {
                const bf16* girow = gi + ((long)(m0 + pmolA[p]) * Aat + a) * 900;
                gr[p] = *(const uint*)(girow + hpA[p]);
                gz[p] = *(const uint*)(girow + 300 + hpA[p]);
                gn[p] = *(const uint*)(girow + 600 + hpA[p]);
            }
        }
        // ---- phase A: gh = Whh @ h (L2-streamed A, LDS B) ----
        short8v hb[10];
        #pragma unroll
        for (int kf = 0; kf < 10; ++kf)
            hb[kf] = *(const short8v*)&Hsb[l15 & (GG5 - 1)][kf * 32 + quad * 8];
        #pragma unroll
        for (int i = 0; i < 4; ++i) {
            const int tile = w + i * 16;
            if (tile < 57) {
                const bf16* ap = WP + (long)(tile * 16 + l15) * 320 + quad * 8;
                float4v acc = (float4v){0.f, 0.f, 0.f, 0.f};
                short8v wfr[5];
                #pragma unroll
                for (int half = 0; half < 2; ++half) {
                    #pragma unroll
                    for (int kf = 0; kf < 5; ++kf)
                        wfr[kf] = *(const short8v*)(ap + (half * 5 + kf) * 32);
                    #pragma unroll
                    for (int kf = 0; kf < 5; ++kf)
                        acc = __builtin_amdgcn_mfma_f32_16x16x32_bf16(
                            wfr[kf], hb[half * 5 + kf], acc, 0, 0, 0);
                }
                if (l15 < GG5)
                    *(float4*)&GHs[l15][tile * 16 + quad * 4] = *(float4*)&acc;
            }
        }
        __syncthreads();
        // ---- phase B: gates + state update, 2 passes ----
        #pragma unroll
        for (int p = 0; p < 2; ++p) {
            if (okA[p]) {
                const int pmol = pmolA[p], hp = hpA[p];
                const float2 hr = *(const float2*)&GHs[pmol][hp];
                const float2 hz = *(const float2*)&GHs[pmol][300 + hp];
                const float2 hn = *(const float2*)&GHs[pmol][600 + hp];
                const float2 hold = *(const float2*)&Hsf[pmol][hp];
                float hnew[2];
                #pragma unroll
                for (int j = 0; j < 2; ++j) {
                    const float ir  = j ? bhi(gr[p]) : blo(gr[p]);
                    const float iz  = j ? bhi(gz[p]) : blo(gz[p]);
                    const float inn = j ? bhi(gn[p]) : blo(gn[p]);
                    const float ghr = (j ? hr.y + brA[p].y : hr.x + brA[p].x);
                    const float ghz = (j ? hz.y + bzA[p].y : hz.x + bzA[p].x);
                    const float ghn = (j ? hn.y + bnA[p].y : hn.x + bnA[p].x);
                    const float rr = 1.f / (1.f + __expf(-(ir + ghr)));
                    const float zz = 1.f / (1.f + __expf(-(iz + ghz)));
                    float nin = inn + rr * ghn;
                    nin = fminf(fmaxf(nin, -15.f), 15.f);
                    const float e2 = __expf(-2.f * nin);
                    const float nnv = (1.f - e2) / (1.f + e2);
                    hnew[j] = (1.f - zz) * nnv + zz * (j ? hold.y : hold.x);
                }
                const uint pk2 = f2bu(hnew[0]) | (f2bu(hnew[1]) << 16);
                *(float2*)&Hsf[pmol][hp] = make_float2(hnew[0], hnew[1]);
                *(uint*)&Hsb[pmol][hp]   = pk2;
                *(uint*)(out + ((long)(m0 + pmol) * Aat + a) * 600 + (long)dir * 300 + hp) = pk2;
            }
        }
        __syncthreads();
    }
}

// =====================================================================
extern "C" void kernel_launch(void* const* d_in, const int* in_sizes, int n_in,
                              void* d_out, int out_size, void* d_ws, size_t ws_size,
                              hipStream_t stream)
{
    (void)in_sizes; (void)n_in; (void)out_size; (void)ws_size;

    const float* f_atoms  = (const float*)d_in[0];
    const float* f_bonds  = (const float*)d_in[1];
    const int*   a2b      = (const int*)d_in[2];
    const int*   b2a      = (const int*)d_in[3];
    const int*   b2revb   = (const int*)d_in[4];
    const float* W_i_atom = (const float*)d_in[7];
    const float* W_i_bond = (const float*)d_in[8];
    const float* W_h      = (const float*)d_in[9];
    const float* lr_W     = (const float*)d_in[10];
    const float* W_o_W    = (const float*)d_in[11];
    const float* W_o_b    = (const float*)d_in[12];
    const float* gWih_f   = (const float*)d_in[13];
    const float* gWhh_f   = (const float*)d_in[14];
    const float* gbih_f   = (const float*)d_in[15];
    const float* gbhh_f   = (const float*)d_in[16];
    const float* gWih_b   = (const float*)d_in[17];
    const float* gWhh_b   = (const float*)d_in[18];
    const float* gbih_b   = (const float*)d_in[19];
    const float* gbhh_b   = (const float*)d_in[20];

    // ---- workspace: same 4-region footprint as proven R6-R8 (~235.9 MB) ----
    const size_t F32A_B = (size_t)NP1 * Hd * 4;      // 39.32 MB
    const size_t BND_B  = (size_t)BP1 * Hd * 2;      // 78.64 MB
    const size_t H0_B   = (size_t)Mmol * Hd * 4;     // 614,400 B
    const size_t WPM_B  = (size_t)1024 * 320 * 2;    // 655,360 B (padded rows)

    size_t off = 0;
    auto alloc = [&](size_t b) { size_t r = off; off += (b + 255) & ~(size_t)255; return r; };
    const size_t r1_o = alloc(F32A_B);       // IA [1-7] -> {H0,WPm,NRb} [8-12] -> AH [13-14]
    const size_t r2_o = alloc(F32A_B);       // MA [3-7] -> GRU [12-13]
    const size_t r3_o = alloc(BND_B);        // IB/MB1 [2-7] -> NODE [8-9] -> GIF [10-12]
    const size_t r4_o = alloc(BND_B + 4096); // FB16 [1b-2] -> MB0 [4-6] -> CC [7-8] -> GIB [11-12]

    char* ws = (char*)d_ws;
    float* IA   = (float*)(ws + r1_o);
    float* H0p  = (float*)(ws + r1_o);
    bf16*  WPmf = (bf16*)(ws + r1_o + ((H0_B + 255) & ~(size_t)255));
    bf16*  WPmb = (bf16*)((char*)WPmf + ((WPM_B + 255) & ~(size_t)255));
    bf16*  NRb  = (bf16*)(ws + r1_o + (2u << 20));   // +2 MB (614K+656K+656K = 1.93 MB used)
    float* AH   = (float*)(ws + r1_o);
    float* MAb  = (float*)(ws + r2_o);
    bf16*  GRU  = (bf16*)(ws + r2_o);
    bf16*  IB   = (bf16*)(ws + r3_o);
    bf16*  MB1  = IB;
    float* NODE = (float*)(ws + r3_o);
    bf16*  GIF  = (bf16*)(ws + r3_o);
    bf16*  FB16 = (bf16*)(ws + r4_o);
    bf16*  MB0  = (bf16*)(ws + r4_o);
    bf16*  CC   = (bf16*)(ws + r4_o);
    bf16*  GIB  = (bf16*)(ws + r4_o);
    float* OUT  = (float*)d_out;
    bf16*  WSC  = (bf16*)d_out;        // 614,400 B time-shared packed-weight scratch

    const dim3 blk(256);
    auto grdF = [](int n, int h) { return dim3((n + BMr - 1) / BMr, (h + BNc - 1) / BNc); };
    auto grdM = [](int n, int h) { return dim3((h + 63) / 64, (n + 127) / 128); };
    auto pk = [&](const float* W, bf16* Wp, int h, int K, long hp, int Kp) {
        const long tot = hp * Kp;
        pack_w<<<dim3((tot + 255) / 256), blk, 0, stream>>>(W, Wp, h, K, tot, Kp);
    };

    // 1. IA = relu(f_atoms @ W_i_atom^T) -> f32 (VALU, full precision)
    gemm_ia<<<grdF(NP1, Hd), blk, 0, stream>>>(f_atoms, W_i_atom, IA, NP1, AF, Hd);
    // 1b. pack f_bonds -> bf16 [BP1][160]; W_i_bond -> [320][160] @d_out
    pk(f_bonds, FB16, BP1, BFd, BP1, 160);
    pk(W_i_bond, WSC, Hd, BFd, 320, 160);
    // 2. IB = relu(FB16 @ WIB^T)   [MFMA]
    mgemm<0, true, false, false, true, false, 0><<<grdM(BP1, Hd), blk, 0, stream>>>(
        FB16, nullptr, nullptr, nullptr, nullptr, WSC, nullptr, nullptr,
        IB, nullptr, BP1, 160, 160, Hd);
    // 3. MA = IA + sum*max(IB gathered)
    agg_kernel<true><<<NP1, 320, 0, stream>>>(IB, a2b, IA, MAb, 0);
    pk(W_h, WSC, Hd, Hd, 320, 320);
    // 4. MB0 = relu(IB + (MA[b2a]-IB[b2revb]) @ Wh0^T)   [MFMA fused gather]
    mgemm<3, true, false, true, true, false, 12><<<grdM(BP1, Hd), blk, 0, stream>>>(
        nullptr, MAb, IB, b2a, b2revb, WSC, nullptr, IB,
        MB0, nullptr, BP1, Hd, 320, Hd);
    // 5. MA += sum*max(MB0 gathered)
    agg_kernel<true><<<NP1, 320, 0, stream>>>(MB0, a2b, MAb, MAb, 0);
    pk(W_h + 300 * 300, WSC, Hd, Hd, 320, 320);
    // 6. MB1(=IB) = relu(IB + (MA[b2a]-MB0[b2revb]) @ Wh1^T)
    mgemm<3, true, false, true, true, false, 12><<<grdM(BP1, Hd), blk, 0, stream>>>(
        nullptr, MAb, MB0, b2a, b2revb, WSC, nullptr, IB,
        MB1, nullptr, BP1, Hd, 320, Hd);
    // 7. CC = concat3 bf16 (agg(MB1) | MA | IA), segment-padded to 960
    cc_build<<<Nat, 320, 0, stream>>>(MB1, a2b, MAb, IA, CC);
    pack_lrw<<<(320 * 960 + 255) / 256, blk, 0, stream>>>(lr_W, WSC);
    // 8. node = CC @ lrWp^T -> NODE f32 (pre-relu) + NRb bf16 (relu)  [MFMA]
    mgemm<0, false, false, false, false, true, 0><<<grdM(Nat, Hd), blk, 0, stream>>>(
        CC, nullptr, nullptr, nullptr, nullptr, WSC, nullptr, nullptr,
        NODE, NRb, Nat, 960, 960, Hd);
    // 9. h0 + GRU Whh packs (r1: IA dead). WP padded to 1024 rows (zeros).
    h0_kernel<<<Mmol, 320, 0, stream>>>(NODE, H0p);
    pk(gWhh_f, WPmf, 900, Hd, 1024, 320);
    pk(gWhh_b, WPmb, 900, Hd, 1024, 320);
    // 10. GIF = NRb @ gWih_f^T + gbih_f   [MFMA]
    pk(gWih_f, WSC, 900, Hd, 960, 320);
    mgemm<0, false, true, false, true, false, 12><<<grdM(Nat, 900), blk, 0, stream>>>(
        NRb, nullptr, nullptr, nullptr, nullptr, WSC, gbih_f, nullptr,
        GIF, nullptr, Nat, Hd, 320, 900);
    // 11. GIB likewise
    pk(gWih_b, WSC, 900, Hd, 960, 320);
    mgemm<0, false, true, false, true, false, 12><<<grdM(Nat, 900), blk, 0, stream>>>(
        NRb, nullptr, nullptr, nullptr, nullptr, WSC, gbih_b, nullptr,
        GIB, nullptr, Nat, Hd, 320, 900);
    // 12. L2-streamed MFMA bidirectional GRU (128 blocks x 1024 thr)
    gru5_kernel<<<(Mmol / GG5) * 2, dim3(1024), 0, stream>>>(
        GIF, GIB, WPmf, WPmb, gbhh_f, gbhh_b, H0p, GRU);
    // 13. AH = relu(GRU @ W_o_W^T + W_o_b)   [MFMA]
    pk(W_o_W, WSC, Hd, 600, 320, 608);
    mgemm<0, true, true, false, false, false, 24><<<grdM(Nat, Hd), blk, 0, stream>>>(
        GRU, nullptr, nullptr, nullptr, nullptr, WSC, W_o_b, nullptr,
        AH, nullptr, Nat, 600, 608, Hd);
    // 14. mol_vecs = mean -> d_out
    mean_kernel<<<Mmol, 320, 0, stream>>>(AH, OUT);
}